// Round 1
// baseline (1027.312 us; speedup 1.0000x reference)
//
#include <hip/hip_runtime.h>
#include <math.h>

#define BN_EPS 1e-5f

// ---------------------------------------------------------------------------
// Problem shape constants
//   x: (16, 640, 32, 32) fp32;  pixels P = 16*32*32 = 16384 (p = b*1024+h*32+w)
//   identity: 64 ch, stored pixel-major ws[p*64 + c]
//   e: 640 ch, stored channel-planar ws[oc*16384 + p]
// ---------------------------------------------------------------------------

// ===========================================================================
// Kernel 1: identity = l2norm_c( relu(bn_in( w_in @ relu(bn1(x)) )) )
// GEMM M=64(all oc) x N=64px x K=640, bn1+relu fused into B load.
// grid 256 blocks (64 contiguous px each), 256 threads, 4x4 per thread.
// ===========================================================================
__global__ __launch_bounds__(256)
void k_identity(const float* __restrict__ x,
                const float* __restrict__ g1, const float* __restrict__ b1,
                const float* __restrict__ m1, const float* __restrict__ v1,
                const float* __restrict__ w_in,
                const float* __restrict__ gi, const float* __restrict__ bi,
                const float* __restrict__ mi, const float* __restrict__ vi,
                float* __restrict__ ident)
{
    __shared__ float As[32 * 64];      // [kk][oc]
    __shared__ float Bs[32 * 64];      // [kk][px]
    __shared__ float T[64 * 68];       // [px][oc] padded
    __shared__ float inv[64];

    const int tid = threadIdx.x;
    const int blk = blockIdx.x;        // 256
    const int p0  = blk * 64;
    const int b   = p0 >> 10;
    const int hw0 = p0 & 1023;

    const int tr = tid >> 4;           // oc group 0..15
    const int tc = tid & 15;           // px group 0..15

    float acc[4][4];
#pragma unroll
    for (int i = 0; i < 4; i++)
#pragma unroll
        for (int j = 0; j < 4; j++) acc[i][j] = 0.f;

    for (int k0 = 0; k0 < 640; k0 += 32) {
        // --- A chunk: w_in[oc][k0+kk] -> As[kk][oc] (transposed store)
#pragma unroll
        for (int e2 = 0; e2 < 2; e2++) {
            int li = e2 * 256 + tid;           // 0..511
            int oc = li >> 3;                  // 0..63
            int kq = li & 7;                   // quad of k
            float4 a = *(const float4*)&w_in[oc * 640 + k0 + kq * 4];
            As[(kq * 4 + 0) * 64 + oc] = a.x;
            As[(kq * 4 + 1) * 64 + oc] = a.y;
            As[(kq * 4 + 2) * 64 + oc] = a.z;
            As[(kq * 4 + 3) * 64 + oc] = a.w;
        }
        // --- B chunk: Bs[kk][px] = relu(bn1(x[b, k0+kk, hw0+px]))
        {
            int kk  = tid >> 3;
            int px0 = (tid & 7) * 8;
            int ch  = k0 + kk;
            float s  = g1[ch] * rsqrtf(v1[ch] + BN_EPS);
            float bb = b1[ch] - m1[ch] * s;
            const float* xp = &x[((size_t)b * 640 + ch) * 1024 + hw0 + px0];
            float4 u0 = *(const float4*)&xp[0];
            float4 u1 = *(const float4*)&xp[4];
            float4 r0, r1;
            r0.x = fmaxf(fmaf(u0.x, s, bb), 0.f);
            r0.y = fmaxf(fmaf(u0.y, s, bb), 0.f);
            r0.z = fmaxf(fmaf(u0.z, s, bb), 0.f);
            r0.w = fmaxf(fmaf(u0.w, s, bb), 0.f);
            r1.x = fmaxf(fmaf(u1.x, s, bb), 0.f);
            r1.y = fmaxf(fmaf(u1.y, s, bb), 0.f);
            r1.z = fmaxf(fmaf(u1.z, s, bb), 0.f);
            r1.w = fmaxf(fmaf(u1.w, s, bb), 0.f);
            *(float4*)&Bs[kk * 64 + px0]     = r0;
            *(float4*)&Bs[kk * 64 + px0 + 4] = r1;
        }
        __syncthreads();
#pragma unroll
        for (int kk = 0; kk < 32; kk++) {
            float4 a  = *(const float4*)&As[kk * 64 + tr * 4];
            float4 bv = *(const float4*)&Bs[kk * 64 + tc * 4];
            float af[4] = {a.x, a.y, a.z, a.w};
            float bf[4] = {bv.x, bv.y, bv.z, bv.w};
#pragma unroll
            for (int i = 0; i < 4; i++)
#pragma unroll
                for (int j = 0; j < 4; j++) acc[i][j] = fmaf(af[i], bf[j], acc[i][j]);
        }
        __syncthreads();
    }

    // --- bn_in + relu, stage to T[px][oc]
    float s4[4], bb4[4];
#pragma unroll
    for (int i = 0; i < 4; i++) {
        int oc = tr * 4 + i;
        s4[i]  = gi[oc] * rsqrtf(vi[oc] + BN_EPS);
        bb4[i] = bi[oc] - mi[oc] * s4[i];
    }
#pragma unroll
    for (int j = 0; j < 4; j++) {
        float4 t;
        t.x = fmaxf(fmaf(acc[0][j], s4[0], bb4[0]), 0.f);
        t.y = fmaxf(fmaf(acc[1][j], s4[1], bb4[1]), 0.f);
        t.z = fmaxf(fmaf(acc[2][j], s4[2], bb4[2]), 0.f);
        t.w = fmaxf(fmaf(acc[3][j], s4[3], bb4[3]), 0.f);
        *(float4*)&T[(tc * 4 + j) * 68 + tr * 4] = t;
    }
    __syncthreads();
    if (tid < 64) {
        float sum = 0.f;
#pragma unroll 8
        for (int c = 0; c < 64; c++) {
            float v = T[tid * 68 + c];
            sum = fmaf(v, v, sum);
        }
        inv[tid] = 1.f / fmaxf(sqrtf(sum), 1e-12f);
    }
    __syncthreads();
    {
        int px = tid >> 2;
        int c0 = (tid & 3) * 16;
        float iv = inv[px];
#pragma unroll
        for (int q = 0; q < 4; q++) {
            float4 t = *(const float4*)&T[px * 68 + c0 + q * 4];
            t.x *= iv; t.y *= iv; t.z *= iv; t.w *= iv;
            *(float4*)&ident[(size_t)(p0 + px) * 64 + c0 + q * 4] = t;
        }
    }
}

// ===========================================================================
// Kernel 2: invD[p] = rsqrt( sum_{c,k} (id[c,q_k]*id[c,p])^2 + 1e-6 )
// grid 256 blocks (one 8x8 spatial tile), 256 threads (4 per pixel).
// ===========================================================================
__global__ __launch_bounds__(256)
void k_invd(const float* __restrict__ ident, float* __restrict__ invD)
{
    __shared__ float slab[144 * 68];   // [spx][c], 12x12 spatial, pad 68

    const int tid = threadIdx.x;
    const int blk = blockIdx.x;        // 256
    const int b   = blk >> 4;
    const int t   = blk & 15;
    const int h0  = (t >> 2) * 8, w0 = (t & 3) * 8;

#pragma unroll
    for (int e2 = 0; e2 < 9; e2++) {
        int idx  = e2 * 256 + tid;     // 0..2303
        int spx  = idx >> 4;
        int quad = idx & 15;
        int r  = (spx / 12) - 2 + h0;
        int cc = (spx % 12) - 2 + w0;
        float4 v = make_float4(0.f, 0.f, 0.f, 0.f);
        if (r >= 0 && r < 32 && cc >= 0 && cc < 32)
            v = *(const float4*)&ident[((size_t)b * 1024 + r * 32 + cc) * 64 + quad * 4];
        *(float4*)&slab[spx * 68 + quad * 4] = v;
    }
    __syncthreads();

    int px = tid >> 2, part = tid & 3;
    int rh = px >> 3, rw = px & 7;
    const float* ctr = &slab[((rh + 2) * 12 + (rw + 2)) * 68];
    float sum = 0.f;
#pragma unroll
    for (int k = 0; k < 25; k++) {
        const int kh = k / 5, kw = k % 5;
        const float* nb = &slab[((rh + kh) * 12 + (rw + kw)) * 68];
#pragma unroll
        for (int ci = 0; ci < 16; ci++) {
            int c = part * 16 + ci;
            float pr = nb[c] * ctr[c];
            sum = fmaf(pr, pr, sum);
        }
    }
    sum += __shfl_xor(sum, 1);
    sum += __shfl_xor(sum, 2);
    if (part == 0)
        invD[b * 1024 + (h0 + rh) * 32 + (w0 + rw)] = rsqrtf(sum + 1e-6f);
}

// ===========================================================================
// Kernel 3: e = relu(bn_e( w_emb @ feat )), feat generated on the fly.
// GEMM M=640 x N=16384 x K=1664. grid (ntile=256, mtile=10), 256 thr, 64x64.
// feat row kg<64: identity[c][p]; kg>=64: r=kg-64, c=r/25, k=r%25,
//   feat = id[c, p+off(k)] * id[c, p] * invD[p]
// ===========================================================================
__global__ __launch_bounds__(256)
void k_emb(const float* __restrict__ ident, const float* __restrict__ invD,
           const float* __restrict__ w_emb,
           const float* __restrict__ ge, const float* __restrict__ be,
           const float* __restrict__ me, const float* __restrict__ ve,
           float* __restrict__ e)
{
    __shared__ float slab[144 * 68];   // 38.3 KB
    __shared__ float As[32 * 64];      // [kk][oc]
    __shared__ float Fs[32 * 68];      // [kk][px] padded
    __shared__ float invDs[64];

    const int tid = threadIdx.x;
    const int nt  = blockIdx.x;        // 256
    const int mt  = blockIdx.y;        // 10
    const int b   = nt >> 4;
    const int t   = nt & 15;
    const int h0  = (t >> 2) * 8, w0 = (t & 3) * 8;

#pragma unroll
    for (int e2 = 0; e2 < 9; e2++) {
        int idx  = e2 * 256 + tid;
        int spx  = idx >> 4;
        int quad = idx & 15;
        int r  = (spx / 12) - 2 + h0;
        int cc = (spx % 12) - 2 + w0;
        float4 v = make_float4(0.f, 0.f, 0.f, 0.f);
        if (r >= 0 && r < 32 && cc >= 0 && cc < 32)
            v = *(const float4*)&ident[((size_t)b * 1024 + r * 32 + cc) * 64 + quad * 4];
        *(float4*)&slab[spx * 68 + quad * 4] = v;
    }
    if (tid < 64) {
        int rh = tid >> 3, rw = tid & 7;
        invDs[tid] = invD[b * 1024 + (h0 + rh) * 32 + (w0 + rw)];
    }
    __syncthreads();

    const int tr = tid >> 4, tc = tid & 15;
    float acc[4][4];
#pragma unroll
    for (int i = 0; i < 4; i++)
#pragma unroll
        for (int j = 0; j < 4; j++) acc[i][j] = 0.f;

    for (int k0 = 0; k0 < 1664; k0 += 32) {
        // --- A chunk: w_emb[mt*64+oc][k0+kk] -> As[kk][oc]
#pragma unroll
        for (int e2 = 0; e2 < 2; e2++) {
            int li = e2 * 256 + tid;
            int oc = li >> 3;
            int kq = li & 7;
            float4 a = *(const float4*)&w_emb[(size_t)(mt * 64 + oc) * 1664 + k0 + kq * 4];
            As[(kq * 4 + 0) * 64 + oc] = a.x;
            As[(kq * 4 + 1) * 64 + oc] = a.y;
            As[(kq * 4 + 2) * 64 + oc] = a.z;
            As[(kq * 4 + 3) * 64 + oc] = a.w;
        }
        // --- feat chunk -> Fs[kk][px]
        if (k0 < 64) {
#pragma unroll
            for (int e2 = 0; e2 < 8; e2++) {
                int idx = e2 * 256 + tid;
                int kk  = (idx & 7) | ((idx >> 9) << 3);
                int px  = (idx >> 3) & 63;
                int c   = k0 + kk;          // 0..63: identity rows
                int rh = px >> 3, rw = px & 7;
                Fs[kk * 68 + px] = slab[((rh + 2) * 12 + (rw + 2)) * 68 + c];
            }
        } else {
#pragma unroll
            for (int e2 = 0; e2 < 8; e2++) {
                int idx = e2 * 256 + tid;
                int kk  = (idx & 7) | ((idx >> 9) << 3);
                int px  = (idx >> 3) & 63;
                int kg  = k0 + kk;
                int rh = px >> 3, rw = px & 7;
                int r  = kg - 64;
                int c  = r / 25;
                int kq = r - c * 25;
                int kh = kq / 5;
                int kw = kq - kh * 5;
                float nbv = slab[((rh + kh) * 12 + (rw + kw)) * 68 + c];
                float cv  = slab[((rh + 2) * 12 + (rw + 2)) * 68 + c];
                Fs[kk * 68 + px] = nbv * cv * invDs[px];
            }
        }
        __syncthreads();
#pragma unroll
        for (int kk = 0; kk < 32; kk++) {
            float4 a = *(const float4*)&As[kk * 64 + tr * 4];
            float4 f = *(const float4*)&Fs[kk * 68 + tc * 4];
            float af[4] = {a.x, a.y, a.z, a.w};
            float bf[4] = {f.x, f.y, f.z, f.w};
#pragma unroll
            for (int i = 0; i < 4; i++)
#pragma unroll
                for (int j = 0; j < 4; j++) acc[i][j] = fmaf(af[i], bf[j], acc[i][j]);
        }
        __syncthreads();
    }

    // --- epilogue: bn_e + relu -> e[oc][p] (channel-planar)
    float s4[4], bb4[4];
#pragma unroll
    for (int i = 0; i < 4; i++) {
        int oc = mt * 64 + tr * 4 + i;
        s4[i]  = ge[oc] * rsqrtf(ve[oc] + BN_EPS);
        bb4[i] = be[oc] - me[oc] * s4[i];
    }
#pragma unroll
    for (int i = 0; i < 4; i++) {
        int oc = mt * 64 + tr * 4 + i;
#pragma unroll
        for (int j = 0; j < 4; j++) {
            int px = tc * 4 + j;
            int rh = px >> 3, rw = px & 7;
            float v = fmaxf(fmaf(acc[i][j], s4[i], bb4[i]), 0.f);
            e[(size_t)oc * 16384 + b * 1024 + (h0 + rh) * 32 + (w0 + rw)] = v;
        }
    }
}

// ===========================================================================
// Kernel 4: out = bn_o( w_out @ e ).  GEMM 640 x 16384 x 640.
// grid (ntile=256, mtile=10), 256 threads, 64x64 tiles.
// ===========================================================================
__global__ __launch_bounds__(256)
void k_out(const float* __restrict__ e, const float* __restrict__ w_out,
           const float* __restrict__ go, const float* __restrict__ bo,
           const float* __restrict__ mo, const float* __restrict__ vo,
           float* __restrict__ out)
{
    __shared__ float As[32 * 64];      // [kk][oc]
    __shared__ float Bs[32 * 64];      // [kk][px]

    const int tid = threadIdx.x;
    const int nt  = blockIdx.x;        // 256
    const int mt  = blockIdx.y;        // 10
    const int p0  = nt * 64;
    const int b   = p0 >> 10;
    const int hw0 = p0 & 1023;

    const int tr = tid >> 4, tc = tid & 15;
    float acc[4][4];
#pragma unroll
    for (int i = 0; i < 4; i++)
#pragma unroll
        for (int j = 0; j < 4; j++) acc[i][j] = 0.f;

    for (int k0 = 0; k0 < 640; k0 += 32) {
#pragma unroll
        for (int e2 = 0; e2 < 2; e2++) {
            int li = e2 * 256 + tid;
            int oc = li >> 3;
            int kq = li & 7;
            float4 a = *(const float4*)&w_out[(size_t)(mt * 64 + oc) * 640 + k0 + kq * 4];
            As[(kq * 4 + 0) * 64 + oc] = a.x;
            As[(kq * 4 + 1) * 64 + oc] = a.y;
            As[(kq * 4 + 2) * 64 + oc] = a.z;
            As[(kq * 4 + 3) * 64 + oc] = a.w;
        }
        {
            int kk  = tid >> 3;
            int px0 = (tid & 7) * 8;
            const float* ep = &e[(size_t)(k0 + kk) * 16384 + p0 + px0];
            *(float4*)&Bs[kk * 64 + px0]     = *(const float4*)&ep[0];
            *(float4*)&Bs[kk * 64 + px0 + 4] = *(const float4*)&ep[4];
        }
        __syncthreads();
#pragma unroll
        for (int kk = 0; kk < 32; kk++) {
            float4 a  = *(const float4*)&As[kk * 64 + tr * 4];
            float4 bv = *(const float4*)&Bs[kk * 64 + tc * 4];
            float af[4] = {a.x, a.y, a.z, a.w};
            float bf[4] = {bv.x, bv.y, bv.z, bv.w};
#pragma unroll
            for (int i = 0; i < 4; i++)
#pragma unroll
                for (int j = 0; j < 4; j++) acc[i][j] = fmaf(af[i], bf[j], acc[i][j]);
        }
        __syncthreads();
    }

    // --- epilogue: bn_o (no relu) -> out[b][oc][hw]
#pragma unroll
    for (int i = 0; i < 4; i++) {
        int oc = mt * 64 + tr * 4 + i;
        float s  = go[oc] * rsqrtf(vo[oc] + BN_EPS);
        float bb = bo[oc] - mo[oc] * s;
        float4 v;
        v.x = fmaf(acc[i][0], s, bb);
        v.y = fmaf(acc[i][1], s, bb);
        v.z = fmaf(acc[i][2], s, bb);
        v.w = fmaf(acc[i][3], s, bb);
        *(float4*)&out[((size_t)b * 640 + oc) * 1024 + hw0 + tc * 4] = v;
    }
}

// ===========================================================================
extern "C" void kernel_launch(void* const* d_in, const int* in_sizes, int n_in,
                              void* d_out, int out_size, void* d_ws, size_t ws_size,
                              hipStream_t stream)
{
    const float* x    = (const float*)d_in[0];
    const float* g1   = (const float*)d_in[1];
    const float* b1   = (const float*)d_in[2];
    const float* m1   = (const float*)d_in[3];
    const float* v1   = (const float*)d_in[4];
    const float* w_in = (const float*)d_in[5];
    const float* gi   = (const float*)d_in[6];
    const float* bi   = (const float*)d_in[7];
    const float* mi   = (const float*)d_in[8];
    const float* vi   = (const float*)d_in[9];
    const float* w_emb= (const float*)d_in[10];
    const float* ge   = (const float*)d_in[11];
    const float* be   = (const float*)d_in[12];
    const float* me   = (const float*)d_in[13];
    const float* ve   = (const float*)d_in[14];
    const float* w_out= (const float*)d_in[15];
    const float* go   = (const float*)d_in[16];
    const float* bo   = (const float*)d_in[17];
    const float* mo   = (const float*)d_in[18];
    const float* vo   = (const float*)d_in[19];

    float* out   = (float*)d_out;
    float* ident = (float*)d_ws;                  // 16384*64   = 4 MB
    float* invD  = ident + (size_t)16384 * 64;    // 16384      = 64 KB
    float* e     = invD + 16384;                  // 640*16384  = 42 MB

    k_identity<<<256, 256, 0, stream>>>(x, g1, b1, m1, v1, w_in, gi, bi, mi, vi, ident);
    k_invd<<<256, 256, 0, stream>>>(ident, invD);
    k_emb<<<dim3(256, 10), 256, 0, stream>>>(ident, invD, w_emb, ge, be, me, ve, e);
    k_out<<<dim3(256, 10), 256, 0, stream>>>(e, w_out, go, bo, mo, vo, out);
}

// Round 4
// 283.460 us; speedup vs baseline: 3.6242x; 3.6242x over previous
//
#include <hip/hip_runtime.h>
#include <math.h>

#define BN_EPS 1e-5f

using short8  = __attribute__((ext_vector_type(8))) short;
using f32x16  = __attribute__((ext_vector_type(16))) float;

// ---------------------------------------------------------------------------
// Shapes: x (16,640,32,32) fp32. Pixels P=16384, p = b*1024 + h*32 + w.
// ident: bf16 [p][64] pixel-major.  e: bf16 [p][640] pixel-major.
// feat K-order (permuted!): kg'<64 -> identity channel kg';
//   kg'>=64: t=kg'-64, ksp=t>>6 (spatial offset 0..24), c=t&63,
//   original w_emb col = 64 + c*25 + ksp.
// Weights pre-tiled in MFMA A-frag slot order:
//   [mt][kc][mf][kh][slot64][8 bf16], element (oc,k):
//   oc = mt*128 + mf*32 + (slot&31), k = kc*32 + kh*16 + (slot>>5)*8 + j
// ---------------------------------------------------------------------------

__device__ __forceinline__ float bflo(unsigned u) { return __uint_as_float(u << 16); }
__device__ __forceinline__ float bfhi(unsigned u) { return __uint_as_float(u & 0xffff0000u); }

// round-to-nearest-even fp32 -> bf16 (no NaN special-casing; inputs are finite)
__device__ __forceinline__ unsigned bf16_rne(float f) {
    unsigned u = __float_as_uint(f);
    return (u + 0x7fffu + ((u >> 16) & 1u)) >> 16;
}
__device__ __forceinline__ unsigned pack_bf16(float lo, float hi) {
    return bf16_rne(lo) | (bf16_rne(hi) << 16);
}
// product of two bf16 pairs -> bf16 pair
__device__ __forceinline__ unsigned pmul(unsigned a, unsigned b) {
    return pack_bf16(bflo(a) * bflo(b), bfhi(a) * bfhi(b));
}

// ===========================================================================
// k_prep: BN folding, bf16 conversion, K-permutation, fragment tiling.
// Ranges: [0,1984) scalars; [2048,7168) wIt (5120 units);
//         [8192,141312) wEt (133120 units); [141312,192512) wOt (51200 units)
// ===========================================================================
__global__ __launch_bounds__(256)
void k_prep(const float* __restrict__ g1, const float* __restrict__ b1,
            const float* __restrict__ m1, const float* __restrict__ v1,
            const float* __restrict__ w_in,
            const float* __restrict__ gi, const float* __restrict__ bi,
            const float* __restrict__ mi, const float* __restrict__ vi,
            const float* __restrict__ w_emb,
            const float* __restrict__ ge, const float* __restrict__ be,
            const float* __restrict__ me, const float* __restrict__ ve,
            const float* __restrict__ w_out,
            const float* __restrict__ go, const float* __restrict__ bo,
            const float* __restrict__ mo, const float* __restrict__ vo,
            float* __restrict__ s1, float* __restrict__ b1c,
            float* __restrict__ biasI, float* __restrict__ biasE, float* __restrict__ biasO,
            unsigned* __restrict__ wIt, unsigned* __restrict__ wEt, unsigned* __restrict__ wOt)
{
    int i = blockIdx.x * 256 + threadIdx.x;

    if (i < 640) {                       // bn1 scale/bias (applied to x)
        float s = g1[i] * rsqrtf(v1[i] + BN_EPS);
        s1[i] = s; b1c[i] = b1[i] - m1[i] * s;
    } else if (i < 704) {                // biasI
        int c = i - 640;
        float s = gi[c] * rsqrtf(vi[c] + BN_EPS);
        biasI[c] = bi[c] - mi[c] * s;
    } else if (i < 1344) {               // biasE
        int c = i - 704;
        float s = ge[c] * rsqrtf(ve[c] + BN_EPS);
        biasE[c] = be[c] - me[c] * s;
    } else if (i < 1984) {               // biasO
        int c = i - 1344;
        float s = go[c] * rsqrtf(vo[c] + BN_EPS);
        biasO[c] = bo[c] - mo[c] * s;
    }

    if (i >= 2048 && i < 7168) {         // wIt: 20 kc x 256 units
        int u = i - 2048;
        int kc = u >> 8, w = u & 255;
        int mf = w >> 7, kh = (w >> 6) & 1, sl = w & 63;
        int oc = mf * 32 + (sl & 31);
        int k0 = kc * 32 + kh * 16 + (sl >> 5) * 8;
        float sc = gi[oc] * rsqrtf(vi[oc] + BN_EPS);
        unsigned d[4];
#pragma unroll
        for (int q = 0; q < 4; q++)
            d[q] = pack_bf16(w_in[oc * 640 + k0 + 2 * q] * sc,
                             w_in[oc * 640 + k0 + 2 * q + 1] * sc);
        ((uint4*)wIt)[u] = make_uint4(d[0], d[1], d[2], d[3]);
    }

    if (i >= 8192 && i < 141312) {       // wEt: 5 mt x 52 kc x 512 units = 133120
        int u = i - 8192;
        int ci = u >> 9, w = u & 511;
        int mt = ci / 52, kc = ci - mt * 52;
        int mf = w >> 7, kh = (w >> 6) & 1, sl = w & 63;
        int oc = mt * 128 + mf * 32 + (sl & 31);
        int k0 = kc * 32 + kh * 16 + (sl >> 5) * 8;
        float sc = ge[oc] * rsqrtf(ve[oc] + BN_EPS);
        float v[8];
#pragma unroll
        for (int j = 0; j < 8; j++) {
            int kgp = k0 + j;
            int orig;
            if (kgp < 64) orig = kgp;
            else { int t = kgp - 64; orig = 64 + (t & 63) * 25 + (t >> 6); }
            v[j] = w_emb[(size_t)oc * 1664 + orig] * sc;
        }
        ((uint4*)wEt)[u] = make_uint4(pack_bf16(v[0], v[1]), pack_bf16(v[2], v[3]),
                                      pack_bf16(v[4], v[5]), pack_bf16(v[6], v[7]));
    }

    if (i >= 141312 && i < 192512) {     // wOt: 5 mt x 20 kc x 512 units = 51200
        int u = i - 141312;
        int ci = u >> 9, w = u & 511;
        int mt = ci / 20, kc = ci - mt * 20;
        int mf = w >> 7, kh = (w >> 6) & 1, sl = w & 63;
        int oc = mt * 128 + mf * 32 + (sl & 31);
        int k0 = kc * 32 + kh * 16 + (sl >> 5) * 8;
        float sc = go[oc] * rsqrtf(vo[oc] + BN_EPS);
        unsigned d[4];
#pragma unroll
        for (int q = 0; q < 4; q++)
            d[q] = pack_bf16(w_out[oc * 640 + k0 + 2 * q] * sc,
                             w_out[oc * 640 + k0 + 2 * q + 1] * sc);
        ((uint4*)wOt)[u] = make_uint4(d[0], d[1], d[2], d[3]);
    }
}

// ===========================================================================
// k_identity: ident[p][64] bf16 = l2norm_c( relu( wI @ relu(bn1(x)) + biasI ) )
// MFMA GEMM M=64 x N=64px x K=640. 256 thr = 4 waves, wave-tile 32x32.
// ===========================================================================
__global__ __launch_bounds__(256, 2)
void k_identity(const float* __restrict__ x,
                const float* __restrict__ s1, const float* __restrict__ b1c,
                const unsigned* __restrict__ wIt, const float* __restrict__ biasI,
                unsigned* __restrict__ ident)
{
    __shared__ short smem[4096];          // Abuf [0,2048) Bbuf [2048,4096)
    __shared__ float T[64 * 68];
    __shared__ float inv[64];

    const int tid = threadIdx.x;
    const int l = tid & 63, wv = tid >> 6;
    const int mf = wv >> 1, nf = wv & 1;
    const int p0 = blockIdx.x * 64;
    const int b = p0 >> 10, hw0 = p0 & 1023;

    f32x16 acc;
#pragma unroll
    for (int r = 0; r < 16; r++) acc[r] = 0.f;

    for (int kc = 0; kc < 20; kc++) {
        // A: pre-tiled, contiguous
        uint4 av = ((const uint4*)wIt)[kc * 256 + tid];
        // B: x -> bn1 -> relu -> bf16, into frag-slot order
        int u = tid;                       // [nf2][kh2][slot64]
        int bnf = u >> 7, bkh = (u >> 6) & 1, sl = u & 63;
        int px = bnf * 32 + (sl & 31);
        int ch0 = kc * 32 + bkh * 16 + (sl >> 5) * 8;
        float4 sA = *(const float4*)&s1[ch0], sB = *(const float4*)&s1[ch0 + 4];
        float4 bA = *(const float4*)&b1c[ch0], bB = *(const float4*)&b1c[ch0 + 4];
        float vv[8];
        const float* xp = &x[((size_t)b * 640 + ch0) * 1024 + hw0 + px];
        vv[0] = fmaxf(fmaf(xp[0], sA.x, bA.x), 0.f);
        vv[1] = fmaxf(fmaf(xp[1024], sA.y, bA.y), 0.f);
        vv[2] = fmaxf(fmaf(xp[2048], sA.z, bA.z), 0.f);
        vv[3] = fmaxf(fmaf(xp[3072], sA.w, bA.w), 0.f);
        vv[4] = fmaxf(fmaf(xp[4096], sB.x, bB.x), 0.f);
        vv[5] = fmaxf(fmaf(xp[5120], sB.y, bB.y), 0.f);
        vv[6] = fmaxf(fmaf(xp[6144], sB.z, bB.z), 0.f);
        vv[7] = fmaxf(fmaf(xp[7168], sB.w, bB.w), 0.f);
        uint4 bvpk = make_uint4(pack_bf16(vv[0], vv[1]), pack_bf16(vv[2], vv[3]),
                                pack_bf16(vv[4], vv[5]), pack_bf16(vv[6], vv[7]));
        __syncthreads();
        ((uint4*)smem)[tid] = av;          // Abuf
        ((uint4*)(smem + 2048))[tid] = bvpk;
        __syncthreads();
#pragma unroll
        for (int kh = 0; kh < 2; kh++) {
            short8 a = *(const short8*)&smem[((mf * 2 + kh) * 64 + l) * 8];
            short8 bb = *(const short8*)&smem[2048 + ((nf * 2 + kh) * 64 + l) * 8];
            acc = __builtin_amdgcn_mfma_f32_32x32x16_bf16(a, bb, acc, 0, 0, 0);
        }
    }
    __syncthreads();
    // epilogue: bias+relu -> T[px][oc]
#pragma unroll
    for (int r = 0; r < 16; r++) {
        int m = mf * 32 + (r & 3) + 8 * (r >> 2) + 4 * (l >> 5);
        int px = nf * 32 + (l & 31);
        T[px * 68 + m] = fmaxf(acc[r] + biasI[m], 0.f);
    }
    __syncthreads();
    if (tid < 64) {
        float sum = 0.f;
#pragma unroll 8
        for (int c = 0; c < 64; c++) { float v = T[tid * 68 + c]; sum = fmaf(v, v, sum); }
        inv[tid] = 1.f / fmaxf(sqrtf(sum), 1e-12f);
    }
    __syncthreads();
    {
        int px = tid >> 2, q = tid & 3;
        float iv = inv[px];
        unsigned d[8];
#pragma unroll
        for (int t = 0; t < 8; t++)
            d[t] = pack_bf16(T[px * 68 + q * 16 + 2 * t] * iv, T[px * 68 + q * 16 + 2 * t + 1] * iv);
        uint4* dst = (uint4*)&ident[((size_t)(p0 + px) * 64 + q * 16) / 2];
        dst[0] = make_uint4(d[0], d[1], d[2], d[3]);
        dst[1] = make_uint4(d[4], d[5], d[6], d[7]);
    }
}

// ===========================================================================
// k_invd: invD[p] = rsqrt( sum_{c,k} (id[c,nb_k]*id[c,p])^2 + 1e-6 )
// 256 blocks (8x8 tile), 256 threads (4/pixel). ident bf16.
// ===========================================================================
__global__ __launch_bounds__(256)
void k_invd(const unsigned* __restrict__ ident, float* __restrict__ invD)
{
    __shared__ short slab[144 * 72];      // 12x12 spx, 64ch +8 pad

    const int tid = threadIdx.x;
    const int blk = blockIdx.x;
    const int b = blk >> 4, t = blk & 15;
    const int h0 = (t >> 2) * 8, w0 = (t & 3) * 8;

#pragma unroll
    for (int it = 0; it < 5; it++) {
        int u = it * 256 + tid;
        if (u < 1152) {
            int spx = u >> 3, q = u & 7;
            int rr = spx / 12, cc = spx - rr * 12;
            int r = h0 + rr - 2, c = w0 + cc - 2;
            uint4 v = make_uint4(0u, 0u, 0u, 0u);
            if (r >= 0 && r < 32 && c >= 0 && c < 32)
                v = *(const uint4*)&ident[((size_t)(b * 1024 + r * 32 + c) * 64 + q * 8) / 2];
            *(uint4*)&slab[spx * 72 + q * 8] = v;
        }
    }
    __syncthreads();

    int px = tid >> 2, part = tid & 3;
    int rh = px >> 3, rw = px & 7;
    // center values for this part's 16 channels, unpacked
    float ctr[16];
    {
        const unsigned* cp = (const unsigned*)&slab[((rh + 2) * 12 + (rw + 2)) * 72 + part * 16];
#pragma unroll
        for (int d = 0; d < 8; d++) { ctr[2 * d] = bflo(cp[d]); ctr[2 * d + 1] = bfhi(cp[d]); }
    }
    float sum = 0.f;
#pragma unroll
    for (int k = 0; k < 25; k++) {
        const int kh = k / 5, kw = k % 5;
        const unsigned* nb = (const unsigned*)&slab[((rh + kh) * 12 + (rw + kw)) * 72 + part * 16];
#pragma unroll
        for (int d = 0; d < 8; d++) {
            float p0 = bflo(nb[d]) * ctr[2 * d];
            float p1 = bfhi(nb[d]) * ctr[2 * d + 1];
            sum = fmaf(p0, p0, sum); sum = fmaf(p1, p1, sum);
        }
    }
    sum += __shfl_xor(sum, 1);
    sum += __shfl_xor(sum, 2);
    if (part == 0)
        invD[b * 1024 + (h0 + rh) * 32 + (w0 + rw)] = rsqrtf(sum + 1e-6f);
}

// ===========================================================================
// k_emb: e[p][640] bf16 = relu( wE @ feat + biasE ), feat generated on the fly.
// grid (nt=128 regions of 8x16 px, mt=5). 256 thr, block-tile 128oc x 128px.
// ===========================================================================
#define SLAB 0          // 240 spx * 72
#define CTRS 17280      // 128 px * 72
#define ABUF 26496      // 4096
#define BBUF 30592      // 4096  (total 34688 shorts)
__global__ __launch_bounds__(256, 2)
void k_emb(const unsigned* __restrict__ ident, const float* __restrict__ invD,
           const unsigned* __restrict__ wEt, const float* __restrict__ biasE,
           unsigned* __restrict__ e)
{
    __shared__ short smem[34688];
    __shared__ float invDs[128];

    const int tid = threadIdx.x;
    const int l = tid & 63, wv = tid >> 6;
    const int mh = wv >> 1, nh = wv & 1;
    const int nt = blockIdx.x, mt = blockIdx.y;
    const int b = nt >> 3, reg = nt & 7;
    const int h0 = (reg >> 1) * 8, w0 = (reg & 1) * 16;

    // ---- slab: 12 rows x 20 cols of 64ch bf16 (region padded by 2)
#pragma unroll
    for (int it = 0; it < 8; it++) {
        int u = it * 256 + tid;
        if (u < 1920) {
            int spx = u >> 3, q = u & 7;
            int rr = spx / 20, cc = spx - rr * 20;
            int r = h0 + rr - 2, c = w0 + cc - 2;
            uint4 v = make_uint4(0u, 0u, 0u, 0u);
            if (r >= 0 && r < 32 && c >= 0 && c < 32)
                v = *(const uint4*)&ident[((size_t)(b * 1024 + r * 32 + c) * 64 + q * 8) / 2];
            *(uint4*)&smem[SLAB + spx * 72 + q * 8] = v;
        }
    }
    if (tid < 128) {
        int rh = tid >> 4, rw = tid & 15;
        invDs[tid] = invD[b * 1024 + (h0 + rh) * 32 + (w0 + rw)];
    }
    __syncthreads();
    // ---- ctr_s[px][c] = ident_ctr * invD (bf16)
#pragma unroll
    for (int it = 0; it < 4; it++) {
        int u = it * 256 + tid;           // 1024 units
        int px = u >> 3, q = u & 7;
        int rh = px >> 4, rw = px & 15;
        int spx = (rh + 2) * 20 + (rw + 2);
        const unsigned* src = (const unsigned*)&smem[SLAB + spx * 72 + q * 8];
        float iv = invDs[px];
        unsigned d[4];
#pragma unroll
        for (int dd = 0; dd < 4; dd++)
            d[dd] = pack_bf16(bflo(src[dd]) * iv, bfhi(src[dd]) * iv);
        *(uint4*)&smem[CTRS + px * 72 + q * 8] = make_uint4(d[0], d[1], d[2], d[3]);
    }
    __syncthreads();

    f32x16 acc[2][2];
#pragma unroll
    for (int i = 0; i < 2; i++)
#pragma unroll
        for (int j = 0; j < 2; j++)
#pragma unroll
            for (int r = 0; r < 16; r++) acc[i][j][r] = 0.f;

    const uint4* gA = (const uint4*)wEt + ((size_t)(mt * 52) << 9);

    for (int kc = 0; kc < 52; kc++) {
        uint4 a0 = gA[(kc << 9) + tid];
        uint4 a1 = gA[(kc << 9) + 256 + tid];
        // ---- feat units (2 per thread) in frag-slot order
        uint4 f[2];
#pragma unroll
        for (int h = 0; h < 2; h++) {
            int u = h * 256 + tid;
            int bnf = u >> 7, bkh = (u >> 6) & 1, sl = u & 63;
            int px = bnf * 32 + (sl & 31);
            int cl = bkh * 16 + (sl >> 5) * 8;
            int rh = px >> 4, rw = px & 15;
            if (kc < 2) {
                int spx = (rh + 2) * 20 + (rw + 2);
                f[h] = *(const uint4*)&smem[SLAB + spx * 72 + kc * 32 + cl];
            } else {
                int idx = kc - 2;
                int ksp = idx >> 1;
                int cb = (idx & 1) * 32 + cl;
                int kho = ksp / 5, kwo = ksp - kho * 5;
                int spx = (rh + kho) * 20 + (rw + kwo);
                const unsigned* nb = (const unsigned*)&smem[SLAB + spx * 72 + cb];
                const unsigned* ct = (const unsigned*)&smem[CTRS + px * 72 + cb];
                f[h] = make_uint4(pmul(nb[0], ct[0]), pmul(nb[1], ct[1]),
                                  pmul(nb[2], ct[2]), pmul(nb[3], ct[3]));
            }
        }
        __syncthreads();
        ((uint4*)&smem[ABUF])[tid] = a0;
        ((uint4*)&smem[ABUF])[tid + 256] = a1;
        ((uint4*)&smem[BBUF])[tid] = f[0];
        ((uint4*)&smem[BBUF])[tid + 256] = f[1];
        __syncthreads();
#pragma unroll
        for (int kh = 0; kh < 2; kh++) {
            short8 av0 = *(const short8*)&smem[ABUF + ((mh * 2 + 0) * 2 + kh) * 512 + l * 8];
            short8 av1 = *(const short8*)&smem[ABUF + ((mh * 2 + 1) * 2 + kh) * 512 + l * 8];
            short8 bv0 = *(const short8*)&smem[BBUF + ((nh * 2 + 0) * 2 + kh) * 512 + l * 8];
            short8 bv1 = *(const short8*)&smem[BBUF + ((nh * 2 + 1) * 2 + kh) * 512 + l * 8];
            acc[0][0] = __builtin_amdgcn_mfma_f32_32x32x16_bf16(av0, bv0, acc[0][0], 0, 0, 0);
            acc[0][1] = __builtin_amdgcn_mfma_f32_32x32x16_bf16(av0, bv1, acc[0][1], 0, 0, 0);
            acc[1][0] = __builtin_amdgcn_mfma_f32_32x32x16_bf16(av1, bv0, acc[1][0], 0, 0, 0);
            acc[1][1] = __builtin_amdgcn_mfma_f32_32x32x16_bf16(av1, bv1, acc[1][1], 0, 0, 0);
        }
    }
    __syncthreads();
    // ---- epilogue: bias+relu -> bf16 pairs into Ep[px][128oc] (overlays slab)
    short* Ep = smem;                      // 128 * 136
#pragma unroll
    for (int mi = 0; mi < 2; mi++)
#pragma unroll
        for (int ni = 0; ni < 2; ni++) {
            int px = (nh * 2 + ni) * 32 + (l & 31);
#pragma unroll
            for (int r = 0; r < 16; r += 2) {
                int m = (mh * 2 + mi) * 32 + (r & 3) + 8 * (r >> 2) + 4 * (l >> 5);
                float v0 = fmaxf(acc[mi][ni][r] + biasE[mt * 128 + m], 0.f);
                float v1 = fmaxf(acc[mi][ni][r + 1] + biasE[mt * 128 + m + 1], 0.f);
                *(unsigned*)&Ep[px * 136 + m] = pack_bf16(v0, v1);
            }
        }
    __syncthreads();
    {
        int px = tid >> 1, half = tid & 1;
        int rh = px >> 4, rw = px & 15;
        size_t gp = (size_t)b * 1024 + (h0 + rh) * 32 + (w0 + rw);
        const uint4* src = (const uint4*)&Ep[px * 136 + half * 64];
        uint4* dst = (uint4*)&e[(gp * 640 + mt * 128 + half * 64) / 2];
#pragma unroll
        for (int q = 0; q < 8; q++) dst[q] = src[q];
    }
}

// ===========================================================================
// k_out: out = wO @ e + biasO (fp32 channel-planar). grid (nt=128, mt=5).
// block-tile 128oc x 128px, K=640.
// ===========================================================================
__global__ __launch_bounds__(256, 2)
void k_out(const unsigned* __restrict__ e, const unsigned* __restrict__ wOt,
           const float* __restrict__ biasO, float* __restrict__ out)
{
    __shared__ short smem[8192];           // Abuf [0,4096) Bbuf [4096,8192)

    const int tid = threadIdx.x;
    const int l = tid & 63, wv = tid >> 6;
    const int mh = wv >> 1, nh = wv & 1;
    const int p0 = blockIdx.x * 128, mt = blockIdx.y;
    const int b = p0 >> 10, hw0 = p0 & 1023;

    f32x16 acc[2][2];
#pragma unroll
    for (int i = 0; i < 2; i++)
#pragma unroll
        for (int j = 0; j < 2; j++)
#pragma unroll
            for (int r = 0; r < 16; r++) acc[i][j][r] = 0.f;

    const uint4* gA = (const uint4*)wOt + ((size_t)(mt * 20) << 9);

    for (int kc = 0; kc < 20; kc++) {
        uint4 a0 = gA[(kc << 9) + tid];
        uint4 a1 = gA[(kc << 9) + 256 + tid];
        uint4 f[2];
#pragma unroll
        for (int h = 0; h < 2; h++) {
            int u = h * 256 + tid;
            int bnf = u >> 7, bkh = (u >> 6) & 1, sl = u & 63;
            int px = bnf * 32 + (sl & 31);
            int koff = kc * 32 + bkh * 16 + (sl >> 5) * 8;
            f[h] = *(const uint4*)&e[((size_t)(p0 + px) * 640 + koff) / 2];
        }
        __syncthreads();
        ((uint4*)smem)[tid] = a0;
        ((uint4*)smem)[tid + 256] = a1;
        ((uint4*)(smem + 4096))[tid] = f[0];
        ((uint4*)(smem + 4096))[tid + 256] = f[1];
        __syncthreads();
#pragma unroll
        for (int kh = 0; kh < 2; kh++) {
            short8 av0 = *(const short8*)&smem[((mh * 2 + 0) * 2 + kh) * 512 + l * 8];
            short8 av1 = *(const short8*)&smem[((mh * 2 + 1) * 2 + kh) * 512 + l * 8];
            short8 bv0 = *(const short8*)&smem[4096 + ((nh * 2 + 0) * 2 + kh) * 512 + l * 8];
            short8 bv1 = *(const short8*)&smem[4096 + ((nh * 2 + 1) * 2 + kh) * 512 + l * 8];
            acc[0][0] = __builtin_amdgcn_mfma_f32_32x32x16_bf16(av0, bv0, acc[0][0], 0, 0, 0);
            acc[0][1] = __builtin_amdgcn_mfma_f32_32x32x16_bf16(av0, bv1, acc[0][1], 0, 0, 0);
            acc[1][0] = __builtin_amdgcn_mfma_f32_32x32x16_bf16(av1, bv0, acc[1][0], 0, 0, 0);
            acc[1][1] = __builtin_amdgcn_mfma_f32_32x32x16_bf16(av1, bv1, acc[1][1], 0, 0, 0);
        }
    }
    // ---- epilogue: bias, fp32 channel-planar out (coalesced over px)
#pragma unroll
    for (int mi = 0; mi < 2; mi++)
#pragma unroll
        for (int ni = 0; ni < 2; ni++) {
            int pxl = (nh * 2 + ni) * 32 + (l & 31);
#pragma unroll
            for (int r = 0; r < 16; r++) {
                int oc = mt * 128 + (mh * 2 + mi) * 32 + (r & 3) + 8 * (r >> 2) + 4 * (l >> 5);
                out[((size_t)b * 640 + oc) * 1024 + hw0 + pxl] = acc[mi][ni][r] + biasO[oc];
            }
        }
}

// ===========================================================================
extern "C" void kernel_launch(void* const* d_in, const int* in_sizes, int n_in,
                              void* d_out, int out_size, void* d_ws, size_t ws_size,
                              hipStream_t stream)
{
    const float* x    = (const float*)d_in[0];
    const float* g1   = (const float*)d_in[1];
    const float* b1   = (const float*)d_in[2];
    const float* m1   = (const float*)d_in[3];
    const float* v1   = (const float*)d_in[4];
    const float* w_in = (const float*)d_in[5];
    const float* gi   = (const float*)d_in[6];
    const float* bi   = (const float*)d_in[7];
    const float* mi   = (const float*)d_in[8];
    const float* vi   = (const float*)d_in[9];
    const float* w_emb= (const float*)d_in[10];
    const float* ge   = (const float*)d_in[11];
    const float* be   = (const float*)d_in[12];
    const float* me   = (const float*)d_in[13];
    const float* ve   = (const float*)d_in[14];
    const float* w_out= (const float*)d_in[15];
    const float* go   = (const float*)d_in[16];
    const float* bo   = (const float*)d_in[17];
    const float* mo   = (const float*)d_in[18];
    const float* vo   = (const float*)d_in[19];

    char* ws = (char*)d_ws;
    float*    s1    = (float*)(ws + 0);
    float*    b1c   = (float*)(ws + 2560);
    float*    biasI = (float*)(ws + 5120);
    float*    biasE = (float*)(ws + 5376);
    float*    biasO = (float*)(ws + 7936);
    unsigned* wIt   = (unsigned*)(ws + 16384);
    unsigned* wOt   = (unsigned*)(ws + 98304);
    unsigned* wEt   = (unsigned*)(ws + 917504);
    unsigned* ident = (unsigned*)(ws + 3047424);
    float*    invD  = (float*)(ws + 5144576);
    unsigned* e     = (unsigned*)(ws + 5210112);
    float*    out   = (float*)d_out;

    k_prep<<<752, 256, 0, stream>>>(g1, b1, m1, v1, w_in, gi, bi, mi, vi,
                                    w_emb, ge, be, me, ve, w_out, go, bo, mo, vo,
                                    s1, b1c, biasI, biasE, biasO, wIt, wEt, wOt);
    k_identity<<<256, 256, 0, stream>>>(x, s1, b1c, wIt, biasI, ident);
    k_invd<<<256, 256, 0, stream>>>(ident, invD);
    k_emb<<<dim3(128, 5), 256, 0, stream>>>(ident, invD, wEt, biasE, e);
    k_out<<<dim3(128, 5), 256, 0, stream>>>(e, wOt, biasO, out);
}

// Round 5
// 231.073 us; speedup vs baseline: 4.4458x; 1.2267x over previous
//
#include <hip/hip_runtime.h>
#include <math.h>

#define BN_EPS 1e-5f

using short8  = __attribute__((ext_vector_type(8))) short;
using f32x16  = __attribute__((ext_vector_type(16))) float;

// ---------------------------------------------------------------------------
// x (16,640,32,32) fp32. Pixels P=16384, p = b*1024 + h*32 + w.
// ident: bf16 [p][64] pixel-major.
// feat K-order (permuted): kg'<64 -> identity ch kg'; kg'>=64: t=kg'-64,
//   ksp=t>>6 (spatial 0..24), c=t&63; orig w_emb col = 64 + c*25 + ksp.
// Weight tiles (A-frag order), per kc (K=32 chunk) 512 uint4 units:
//   u = (mf*2+kh)*64 + sl;  oc = mt*128 + mf*32 + (sl&31),
//   k = kc*32 + kh*16 + (sl>>5)*8 + j   (8 bf16 per unit)
// featG (B-frag order): [pt:256][kc:52][u:256],
//   u = (hf<<7)|(bkh<<6)|sl; px = pt*64 + hf*32 + (sl&31),
//   kg' = kc*32 + bkh*16 + (sl>>5)*8 + j
// eG (B-frag order for k_out): [pt:256][kc:20][u:256], same u scheme, k=oc.
// ---------------------------------------------------------------------------

__device__ __forceinline__ float bflo(unsigned u) { return __uint_as_float(u << 16); }
__device__ __forceinline__ float bfhi(unsigned u) { return __uint_as_float(u & 0xffff0000u); }

// RNE pack (weight prep / identity quality path)
__device__ __forceinline__ unsigned bf16_rne(float f) {
    unsigned u = __float_as_uint(f);
    return (u + 0x7fffu + ((u >> 16) & 1u)) >> 16;
}
__device__ __forceinline__ unsigned pack_bf16(float lo, float hi) {
    return bf16_rne(lo) | (bf16_rne(hi) << 16);
}
// fast pack: round-half-up + byte-perm (3 VALU ops per pair)
__device__ __forceinline__ unsigned pk_hu(float lo, float hi) {
    unsigned a = __float_as_uint(lo) + 0x8000u;
    unsigned b = __float_as_uint(hi) + 0x8000u;
    return __builtin_amdgcn_perm(b, a, 0x07060302u);
}
__device__ __forceinline__ unsigned pmul_fast(unsigned a, unsigned b) {
    return pk_hu(bflo(a) * bflo(b), bfhi(a) * bfhi(b));
}

// ===========================================================================
// k_prep: scalars + wIt + wOt.
// [0,1984) scalars; [2048,7168) wIt; [8192,59392) wOt.  grid 232x256
// ===========================================================================
__global__ __launch_bounds__(256)
void k_prep(const float* __restrict__ g1, const float* __restrict__ b1,
            const float* __restrict__ m1, const float* __restrict__ v1,
            const float* __restrict__ w_in,
            const float* __restrict__ gi, const float* __restrict__ bi,
            const float* __restrict__ mi, const float* __restrict__ vi,
            const float* __restrict__ ge, const float* __restrict__ be,
            const float* __restrict__ me, const float* __restrict__ ve,
            const float* __restrict__ w_out,
            const float* __restrict__ go, const float* __restrict__ bo,
            const float* __restrict__ mo, const float* __restrict__ vo,
            float* __restrict__ s1, float* __restrict__ b1c,
            float* __restrict__ biasI, float* __restrict__ biasE, float* __restrict__ biasO,
            unsigned* __restrict__ wIt, unsigned* __restrict__ wOt)
{
    int i = blockIdx.x * 256 + threadIdx.x;

    if (i < 640) {
        float s = g1[i] * rsqrtf(v1[i] + BN_EPS);
        s1[i] = s; b1c[i] = b1[i] - m1[i] * s;
    } else if (i < 704) {
        int c = i - 640;
        float s = gi[c] * rsqrtf(vi[c] + BN_EPS);
        biasI[c] = bi[c] - mi[c] * s;
    } else if (i < 1344) {
        int c = i - 704;
        float s = ge[c] * rsqrtf(ve[c] + BN_EPS);
        biasE[c] = be[c] - me[c] * s;
    } else if (i < 1984) {
        int c = i - 1344;
        float s = go[c] * rsqrtf(vo[c] + BN_EPS);
        biasO[c] = bo[c] - mo[c] * s;
    }

    if (i >= 2048 && i < 7168) {         // wIt: 20 kc x 256 units
        int u = i - 2048;
        int kc = u >> 8, w = u & 255;
        int mf = w >> 7, kh = (w >> 6) & 1, sl = w & 63;
        int oc = mf * 32 + (sl & 31);
        int k0 = kc * 32 + kh * 16 + (sl >> 5) * 8;
        float sc = gi[oc] * rsqrtf(vi[oc] + BN_EPS);
        unsigned d[4];
#pragma unroll
        for (int q = 0; q < 4; q++)
            d[q] = pack_bf16(w_in[oc * 640 + k0 + 2 * q] * sc,
                             w_in[oc * 640 + k0 + 2 * q + 1] * sc);
        ((uint4*)wIt)[u] = make_uint4(d[0], d[1], d[2], d[3]);
    }

    if (i >= 8192 && i < 59392) {        // wOt: 5 mt x 20 kc x 512 units
        int u = i - 8192;
        int ci = u >> 9, w = u & 511;
        int mt = ci / 20, kc = ci - mt * 20;
        int mf = w >> 7, kh = (w >> 6) & 1, sl = w & 63;
        int oc = mt * 128 + mf * 32 + (sl & 31);
        int k0 = kc * 32 + kh * 16 + (sl >> 5) * 8;
        float sc = go[oc] * rsqrtf(vo[oc] + BN_EPS);
        unsigned d[4];
#pragma unroll
        for (int q = 0; q < 4; q++)
            d[q] = pack_bf16(w_out[oc * 640 + k0 + 2 * q] * sc,
                             w_out[oc * 640 + k0 + 2 * q + 1] * sc);
        ((uint4*)wOt)[u] = make_uint4(d[0], d[1], d[2], d[3]);
    }
}

// ===========================================================================
// k_prepE: wEt via per-oc LDS staged row (coalesced w_emb reads). 640 blocks.
// ===========================================================================
__global__ __launch_bounds__(256)
void k_prepE(const float* __restrict__ w_emb,
             const float* __restrict__ ge, const float* __restrict__ ve,
             unsigned* __restrict__ wEt)
{
    __shared__ float row[1664];
    const int tid = threadIdx.x;
    const int oc = blockIdx.x;

#pragma unroll
    for (int it = 0; it < 2; it++) {
        int u = it * 256 + tid;
        if (u < 416)
            ((float4*)row)[u] = ((const float4*)&w_emb[(size_t)oc * 1664])[u];
    }
    __syncthreads();

    if (tid < 208) {
        int kc = tid >> 2, kh = (tid >> 1) & 1, ksub = tid & 1;
        int k0 = kc * 32 + kh * 16 + ksub * 8;
        float sc = ge[oc] * rsqrtf(ve[oc] + BN_EPS);
        float v[8];
#pragma unroll
        for (int j = 0; j < 8; j++) {
            int kgp = k0 + j;
            int orig;
            if (kgp < 64) orig = kgp;
            else { int t = kgp - 64; orig = 64 + (t & 63) * 25 + (t >> 6); }
            v[j] = row[orig] * sc;
        }
        int mt = oc >> 7, mf = (oc >> 5) & 3;
        int idx = (mt * 52 + kc) * 512 + (mf * 2 + kh) * 64 + ksub * 32 + (oc & 31);
        ((uint4*)wEt)[idx] = make_uint4(pack_bf16(v[0], v[1]), pack_bf16(v[2], v[3]),
                                        pack_bf16(v[4], v[5]), pack_bf16(v[6], v[7]));
    }
}

// ===========================================================================
// k_identity: ident[p][64] bf16 = l2norm_c( relu( wI @ relu(bn1(x)) + biasI ) )
// ===========================================================================
__global__ __launch_bounds__(256, 2)
void k_identity(const float* __restrict__ x,
                const float* __restrict__ s1, const float* __restrict__ b1c,
                const unsigned* __restrict__ wIt, const float* __restrict__ biasI,
                unsigned* __restrict__ ident)
{
    __shared__ short smem[4096];
    __shared__ float T[64 * 68];
    __shared__ float inv[64];

    const int tid = threadIdx.x;
    const int l = tid & 63, wv = tid >> 6;
    const int mf = wv >> 1, nf = wv & 1;
    const int p0 = blockIdx.x * 64;
    const int b = p0 >> 10, hw0 = p0 & 1023;

    f32x16 acc;
#pragma unroll
    for (int r = 0; r < 16; r++) acc[r] = 0.f;

    for (int kc = 0; kc < 20; kc++) {
        uint4 av = ((const uint4*)wIt)[kc * 256 + tid];
        int u = tid;
        int bnf = u >> 7, bkh = (u >> 6) & 1, sl = u & 63;
        int px = bnf * 32 + (sl & 31);
        int ch0 = kc * 32 + bkh * 16 + (sl >> 5) * 8;
        float4 sA = *(const float4*)&s1[ch0], sB = *(const float4*)&s1[ch0 + 4];
        float4 bA = *(const float4*)&b1c[ch0], bB = *(const float4*)&b1c[ch0 + 4];
        float vv[8];
        const float* xp = &x[((size_t)b * 640 + ch0) * 1024 + hw0 + px];
        vv[0] = fmaxf(fmaf(xp[0], sA.x, bA.x), 0.f);
        vv[1] = fmaxf(fmaf(xp[1024], sA.y, bA.y), 0.f);
        vv[2] = fmaxf(fmaf(xp[2048], sA.z, bA.z), 0.f);
        vv[3] = fmaxf(fmaf(xp[3072], sA.w, bA.w), 0.f);
        vv[4] = fmaxf(fmaf(xp[4096], sB.x, bB.x), 0.f);
        vv[5] = fmaxf(fmaf(xp[5120], sB.y, bB.y), 0.f);
        vv[6] = fmaxf(fmaf(xp[6144], sB.z, bB.z), 0.f);
        vv[7] = fmaxf(fmaf(xp[7168], sB.w, bB.w), 0.f);
        uint4 bvpk = make_uint4(pack_bf16(vv[0], vv[1]), pack_bf16(vv[2], vv[3]),
                                pack_bf16(vv[4], vv[5]), pack_bf16(vv[6], vv[7]));
        __syncthreads();
        ((uint4*)smem)[tid] = av;
        ((uint4*)(smem + 2048))[tid] = bvpk;
        __syncthreads();
#pragma unroll
        for (int kh = 0; kh < 2; kh++) {
            short8 a = *(const short8*)&smem[((mf * 2 + kh) * 64 + l) * 8];
            short8 bb = *(const short8*)&smem[2048 + ((nf * 2 + kh) * 64 + l) * 8];
            acc = __builtin_amdgcn_mfma_f32_32x32x16_bf16(a, bb, acc, 0, 0, 0);
        }
    }
    __syncthreads();
#pragma unroll
    for (int r = 0; r < 16; r++) {
        int m = mf * 32 + (r & 3) + 8 * (r >> 2) + 4 * (l >> 5);
        int px = nf * 32 + (l & 31);
        T[px * 68 + m] = fmaxf(acc[r] + biasI[m], 0.f);
    }
    __syncthreads();
    if (tid < 64) {
        float sum = 0.f;
#pragma unroll 8
        for (int c = 0; c < 64; c++) { float v = T[tid * 68 + c]; sum = fmaf(v, v, sum); }
        inv[tid] = 1.f / fmaxf(sqrtf(sum), 1e-12f);
    }
    __syncthreads();
    {
        int px = tid >> 2, q = tid & 3;
        float iv = inv[px];
        unsigned d[8];
#pragma unroll
        for (int t = 0; t < 8; t++)
            d[t] = pack_bf16(T[px * 68 + q * 16 + 2 * t] * iv, T[px * 68 + q * 16 + 2 * t + 1] * iv);
        uint4* dst = (uint4*)&ident[((size_t)(p0 + px) * 64 + q * 16) / 2];
        dst[0] = make_uint4(d[0], d[1], d[2], d[3]);
        dst[1] = make_uint4(d[4], d[5], d[6], d[7]);
    }
}

// ===========================================================================
// k_feat: per 64-px tile: slab(6x36 halo) -> invD (folded k_invd) -> ctrs ->
// 52 kc of feat units written to featC in B-frag order. No K-loop barriers.
// ===========================================================================
#define FS_SLAB 0          // 216 spx * 72 shorts
#define FS_CTRS 15552      // 64 px * 72 shorts   (total 20160 shorts)
__global__ __launch_bounds__(256, 3)
void k_feat(const unsigned* __restrict__ ident, unsigned* __restrict__ featC, int ptBase)
{
    __shared__ short smem[20160];
    __shared__ float invDs[64];

    const int tid = threadIdx.x;
    const int pt = ptBase + blockIdx.x;
    const int b = pt >> 4, r0 = (pt & 15) * 2;

    // ---- slab load (zero-padded halo)
#pragma unroll
    for (int it = 0; it < 7; it++) {
        int u = it * 256 + tid;
        if (u < 1728) {
            int spx = u >> 3, q = u & 7;
            int sr = spx / 36, sc = spx - sr * 36;
            int r = r0 + sr - 2, c = sc - 2;
            uint4 v = make_uint4(0u, 0u, 0u, 0u);
            if (r >= 0 && r < 32 && c >= 0 && c < 32)
                v = *(const uint4*)&ident[((size_t)(b * 1024 + r * 32 + c) * 64 + q * 8) / 2];
            *(uint4*)&smem[FS_SLAB + spx * 72 + q * 8] = v;
        }
    }
    __syncthreads();

    // ---- invD (former k_invd): 4 threads / px
    {
        int px = tid >> 2, part = tid & 3;
        int rh = px >> 5, rw = px & 31;
        float ctr[16];
        const unsigned* cp = (const unsigned*)&smem[FS_SLAB + ((rh + 2) * 36 + rw + 2) * 72 + part * 16];
#pragma unroll
        for (int d = 0; d < 8; d++) { ctr[2 * d] = bflo(cp[d]); ctr[2 * d + 1] = bfhi(cp[d]); }
        float sum = 0.f;
#pragma unroll
        for (int k = 0; k < 25; k++) {
            const int kh = k / 5, kw = k % 5;
            const unsigned* nb = (const unsigned*)&smem[FS_SLAB + ((rh + kh) * 36 + rw + kw) * 72 + part * 16];
#pragma unroll
            for (int d = 0; d < 8; d++) {
                float q0 = bflo(nb[d]) * ctr[2 * d];
                float q1 = bfhi(nb[d]) * ctr[2 * d + 1];
                sum = fmaf(q0, q0, sum); sum = fmaf(q1, q1, sum);
            }
        }
        sum += __shfl_xor(sum, 1);
        sum += __shfl_xor(sum, 2);
        if (part == 0) invDs[px] = rsqrtf(sum + 1e-6f);
    }
    __syncthreads();

    // ---- ctrs = center * invD (bf16)
#pragma unroll
    for (int it = 0; it < 2; it++) {
        int u = it * 256 + tid;
        int px = u >> 3, q = u & 7;
        int spx = ((px >> 5) + 2) * 36 + (px & 31) + 2;
        const unsigned* src = (const unsigned*)&smem[FS_SLAB + spx * 72 + q * 8];
        float iv = invDs[px];
        unsigned d[4];
#pragma unroll
        for (int dd = 0; dd < 4; dd++)
            d[dd] = pk_hu(bflo(src[dd]) * iv, bfhi(src[dd]) * iv);
        *(uint4*)&smem[FS_CTRS + px * 72 + q * 8] = make_uint4(d[0], d[1], d[2], d[3]);
    }
    __syncthreads();

    // ---- feat gen: 1 uint4 / thread / kc, stores in B-frag order
    const int hf = tid >> 7, bkh = (tid >> 6) & 1, sl = tid & 63;
    const int pxl = hf * 32 + (sl & 31);
    const int cl = bkh * 16 + (sl >> 5) * 8;
    const int spxC = (hf + 2) * 36 + (sl & 31) + 2;
    uint4* dst = (uint4*)featC + (size_t)blockIdx.x * 52 * 256 + tid;

    for (int kc = 0; kc < 52; kc++) {
        uint4 f;
        if (kc < 2) {
            f = *(const uint4*)&smem[FS_SLAB + spxC * 72 + kc * 32 + cl];
        } else {
            int idx = kc - 2;
            int ksp = idx >> 1;
            int cb = (idx & 1) * 32 + cl;
            int kho = ksp / 5, kwo = ksp - kho * 5;
            int spx = (hf + kho) * 36 + (sl & 31) + kwo;
            const unsigned* nb = (const unsigned*)&smem[FS_SLAB + spx * 72 + cb];
            const unsigned* ct = (const unsigned*)&smem[FS_CTRS + pxl * 72 + cb];
            f = make_uint4(pmul_fast(nb[0], ct[0]), pmul_fast(nb[1], ct[1]),
                           pmul_fast(nb[2], ct[2]), pmul_fast(nb[3], ct[3]));
        }
        dst[kc * 256] = f;
    }
}

// ===========================================================================
// k_emb: pure GEMM, A/B direct from pre-tiled global, no K-loop barriers.
// grid (nt, mt=5). Epilogue re-tiles e into k_out B-frag order via LDS.
// ===========================================================================
__global__ __launch_bounds__(256, 4)
void k_emb(const unsigned* __restrict__ featC, const unsigned* __restrict__ wEt,
           const float* __restrict__ biasE, unsigned* __restrict__ eG, int ntBase)
{
    __shared__ short Ep[128 * 136];

    const int tid = threadIdx.x;
    const int l = tid & 63, wv = tid >> 6;
    const int mh = wv >> 1, nh = wv & 1;
    const int ntL = blockIdx.x, mt = blockIdx.y;

    f32x16 acc[2][2];
#pragma unroll
    for (int i = 0; i < 2; i++)
#pragma unroll
        for (int j = 0; j < 2; j++)
#pragma unroll
            for (int r = 0; r < 16; r++) acc[i][j][r] = 0.f;

    const uint4* A = (const uint4*)wEt + (size_t)(mt * 52) * 512;
    const uint4* B = (const uint4*)featC + (size_t)ntL * 2 * 52 * 256;

    for (int kc = 0; kc < 52; kc++) {
        uint4 av[2][2], bv[2][2];
#pragma unroll
        for (int mi = 0; mi < 2; mi++)
#pragma unroll
            for (int kh = 0; kh < 2; kh++)
                av[mi][kh] = A[(size_t)kc * 512 + ((mh * 2 + mi) * 2 + kh) * 64 + l];
#pragma unroll
        for (int ni = 0; ni < 2; ni++) {
            int bnf = 2 * nh + ni;
#pragma unroll
            for (int kh = 0; kh < 2; kh++)
                bv[ni][kh] = B[((size_t)(bnf >> 1) * 52 + kc) * 256 + ((bnf & 1) << 7) + (kh << 6) + l];
        }
#pragma unroll
        for (int kh = 0; kh < 2; kh++) {
            acc[0][0] = __builtin_amdgcn_mfma_f32_32x32x16_bf16(*(short8*)&av[0][kh], *(short8*)&bv[0][kh], acc[0][0], 0, 0, 0);
            acc[0][1] = __builtin_amdgcn_mfma_f32_32x32x16_bf16(*(short8*)&av[0][kh], *(short8*)&bv[1][kh], acc[0][1], 0, 0, 0);
            acc[1][0] = __builtin_amdgcn_mfma_f32_32x32x16_bf16(*(short8*)&av[1][kh], *(short8*)&bv[0][kh], acc[1][0], 0, 0, 0);
            acc[1][1] = __builtin_amdgcn_mfma_f32_32x32x16_bf16(*(short8*)&av[1][kh], *(short8*)&bv[1][kh], acc[1][1], 0, 0, 0);
        }
    }

    // ---- epilogue: bias+relu -> Ep[px][136]
#pragma unroll
    for (int mi = 0; mi < 2; mi++)
#pragma unroll
        for (int ni = 0; ni < 2; ni++) {
            int px = (nh * 2 + ni) * 32 + (l & 31);
#pragma unroll
            for (int r = 0; r < 16; r += 2) {
                int m = (mh * 2 + mi) * 32 + (r & 3) + 8 * (r >> 2) + 4 * (l >> 5);
                float v0 = fmaxf(acc[mi][ni][r] + biasE[mt * 128 + m], 0.f);
                float v1 = fmaxf(acc[mi][ni][r + 1] + biasE[mt * 128 + m + 1], 0.f);
                *(unsigned*)&Ep[px * 136 + m] = pack_bf16(v0, v1);
            }
        }
    __syncthreads();
    // ---- write e in k_out B-frag order
#pragma unroll
    for (int it = 0; it < 8; it++) {
        int w = it * 256 + tid;
        int oct = w >> 7, pxl = w & 127;
        uint4 v = *(const uint4*)&Ep[pxl * 136 + oct * 8];
        int kcp = mt * 4 + (oct >> 2);
        int bkh = (oct >> 1) & 1, ksub = oct & 1;
        int ptg = (ntBase + ntL) * 2 + (pxl >> 6);
        int hf = (pxl >> 5) & 1, sl2 = ksub * 32 + (pxl & 31);
        ((uint4*)eG)[((size_t)ptg * 20 + kcp) * 256 + (hf << 7) + (bkh << 6) + sl2] = v;
    }
}

// ===========================================================================
// k_out: pure GEMM (wOt x eG), no LDS, no barriers. grid (128, 5).
// ===========================================================================
__global__ __launch_bounds__(256, 4)
void k_out(const unsigned* __restrict__ eG, const unsigned* __restrict__ wOt,
           const float* __restrict__ biasO, float* __restrict__ out)
{
    const int tid = threadIdx.x;
    const int l = tid & 63, wv = tid >> 6;
    const int mh = wv >> 1, nh = wv & 1;
    const int nt = blockIdx.x, mt = blockIdx.y;
    const int p0 = nt * 128;
    const int b = p0 >> 10, hw0 = p0 & 1023;

    f32x16 acc[2][2];
#pragma unroll
    for (int i = 0; i < 2; i++)
#pragma unroll
        for (int j = 0; j < 2; j++)
#pragma unroll
            for (int r = 0; r < 16; r++) acc[i][j][r] = 0.f;

    const uint4* A = (const uint4*)wOt + (size_t)(mt * 20) * 512;
    const uint4* B = (const uint4*)eG + (size_t)nt * 2 * 20 * 256;

    for (int kc = 0; kc < 20; kc++) {
        uint4 av[2][2], bv[2][2];
#pragma unroll
        for (int mi = 0; mi < 2; mi++)
#pragma unroll
            for (int kh = 0; kh < 2; kh++)
                av[mi][kh] = A[(size_t)kc * 512 + ((mh * 2 + mi) * 2 + kh) * 64 + l];
#pragma unroll
        for (int ni = 0; ni < 2; ni++) {
            int bnf = 2 * nh + ni;
#pragma unroll
            for (int kh = 0; kh < 2; kh++)
                bv[ni][kh] = B[((size_t)(bnf >> 1) * 20 + kc) * 256 + ((bnf & 1) << 7) + (kh << 6) + l];
        }
#pragma unroll
        for (int kh = 0; kh < 2; kh++) {
            acc[0][0] = __builtin_amdgcn_mfma_f32_32x32x16_bf16(*(short8*)&av[0][kh], *(short8*)&bv[0][kh], acc[0][0], 0, 0, 0);
            acc[0][1] = __builtin_amdgcn_mfma_f32_32x32x16_bf16(*(short8*)&av[0][kh], *(short8*)&bv[1][kh], acc[0][1], 0, 0, 0);
            acc[1][0] = __builtin_amdgcn_mfma_f32_32x32x16_bf16(*(short8*)&av[1][kh], *(short8*)&bv[0][kh], acc[1][0], 0, 0, 0);
            acc[1][1] = __builtin_amdgcn_mfma_f32_32x32x16_bf16(*(short8*)&av[1][kh], *(short8*)&bv[1][kh], acc[1][1], 0, 0, 0);
        }
    }
#pragma unroll
    for (int mi = 0; mi < 2; mi++)
#pragma unroll
        for (int ni = 0; ni < 2; ni++) {
            int pxl = (nh * 2 + ni) * 32 + (l & 31);
#pragma unroll
            for (int r = 0; r < 16; r++) {
                int oc = mt * 128 + (mh * 2 + mi) * 32 + (r & 3) + 8 * (r >> 2) + 4 * (l >> 5);
                out[((size_t)b * 640 + oc) * 1024 + hw0 + pxl] = acc[mi][ni][r] + biasO[oc];
            }
        }
}

// ===========================================================================
extern "C" void kernel_launch(void* const* d_in, const int* in_sizes, int n_in,
                              void* d_out, int out_size, void* d_ws, size_t ws_size,
                              hipStream_t stream)
{
    const float* x    = (const float*)d_in[0];
    const float* g1   = (const float*)d_in[1];
    const float* b1   = (const float*)d_in[2];
    const float* m1   = (const float*)d_in[3];
    const float* v1   = (const float*)d_in[4];
    const float* w_in = (const float*)d_in[5];
    const float* gi   = (const float*)d_in[6];
    const float* bi   = (const float*)d_in[7];
    const float* mi   = (const float*)d_in[8];
    const float* vi   = (const float*)d_in[9];
    const float* w_emb= (const float*)d_in[10];
    const float* ge   = (const float*)d_in[11];
    const float* be   = (const float*)d_in[12];
    const float* me   = (const float*)d_in[13];
    const float* ve   = (const float*)d_in[14];
    const float* w_out= (const float*)d_in[15];
    const float* go   = (const float*)d_in[16];
    const float* bo   = (const float*)d_in[17];
    const float* mo   = (const float*)d_in[18];
    const float* vo   = (const float*)d_in[19];

    char* ws = (char*)d_ws;
    float*    s1    = (float*)(ws + 0);
    float*    b1c   = (float*)(ws + 2560);
    float*    biasI = (float*)(ws + 5120);
    float*    biasE = (float*)(ws + 5376);
    float*    biasO = (float*)(ws + 7936);
    unsigned* wIt   = (unsigned*)(ws + 16384);
    unsigned* wOt   = (unsigned*)(ws + 98304);
    unsigned* wEt   = (unsigned*)(ws + 917504);
    unsigned* ident = (unsigned*)(ws + 3047424);
    unsigned* eG    = (unsigned*)(ws + 5144576);   // 20,971,520 B -> ends 26,116,096
    float*    out   = (float*)d_out;

    const size_t featFullOff = 26116096ull;
    const size_t featFullBytes = 256ull * 52 * 256 * 16;   // 54,525,952

    k_prep<<<232, 256, 0, stream>>>(g1, b1, m1, v1, w_in, gi, bi, mi, vi,
                                    ge, be, me, ve, w_out, go, bo, mo, vo,
                                    s1, b1c, biasI, biasE, biasO, wIt, wOt);
    k_prepE<<<640, 256, 0, stream>>>(w_emb, ge, ve, wEt);
    k_identity<<<256, 256, 0, stream>>>(x, s1, b1c, wIt, biasI, ident);

    if (ws_size >= featFullOff + featFullBytes) {
        // full featG path: one k_feat + one k_emb
        unsigned* featC = (unsigned*)(ws + featFullOff);
        k_feat<<<256, 256, 0, stream>>>(ident, featC, 0);
        k_emb<<<dim3(128, 5), 256, 0, stream>>>(featC, wEt, biasE, eG, 0);
    } else {
        // chunked fallback: featG chunk (4 tiles) lives in the dead wIt/wOt
        // region [16384, 16384+851968); wOt is regenerated afterwards.
        unsigned* featC = (unsigned*)(ws + 16384);
        for (int c = 0; c < 64; c++) {
            k_feat<<<4, 256, 0, stream>>>(ident, featC, c * 4);
            k_emb<<<dim3(2, 5), 256, 0, stream>>>(featC, wEt, biasE, eG, c * 2);
        }
        k_prep<<<232, 256, 0, stream>>>(g1, b1, m1, v1, w_in, gi, bi, mi, vi,
                                        ge, be, me, ve, w_out, go, bo, mo, vo,
                                        s1, b1c, biasI, biasE, biasO, wIt, wOt);
    }
    k_out<<<dim3(128, 5), 256, 0, stream>>>(eG, wOt, biasO, out);
}

// Round 6
// 230.526 us; speedup vs baseline: 4.4564x; 1.0024x over previous
//
#include <hip/hip_runtime.h>
#include <math.h>

#define BN_EPS 1e-5f

using short8  = __attribute__((ext_vector_type(8))) short;
using f32x16  = __attribute__((ext_vector_type(16))) float;

// ---------------------------------------------------------------------------
// x (16,640,32,32) fp32. Pixels P=16384, p = b*1024 + h*32 + w.
// ident: bf16 [p][64] pixel-major.
// feat K-order (permuted): kg'<64 -> identity ch kg'; kg'>=64: t=kg'-64,
//   ksp=t>>6 (spatial 0..24), c=t&63; orig w_emb col = 64 + c*25 + ksp.
// Weight tiles (A-frag order), per kc (K=32 chunk) 512 uint4 units:
//   u = (mf*2+kh)*64 + sl;  oc = mt*128 + mf*32 + (sl&31),
//   k = kc*32 + kh*16 + (sl>>5)*8 + j   (8 bf16 per unit)
// featG (B-frag order): [pt:256][kc:52][u:256],
//   u = (hf<<7)|(bkh<<6)|sl; px = pt*64 + hf*32 + (sl&31),
//   kg' = kc*32 + bkh*16 + (sl>>5)*8 + j
// eG (B-frag order for k_out): [pt:256][kc:20][u:256], same u scheme, k=oc.
// ---------------------------------------------------------------------------

__device__ __forceinline__ float bflo(unsigned u) { return __uint_as_float(u << 16); }
__device__ __forceinline__ float bfhi(unsigned u) { return __uint_as_float(u & 0xffff0000u); }

__device__ __forceinline__ unsigned bf16_rne(float f) {
    unsigned u = __float_as_uint(f);
    return (u + 0x7fffu + ((u >> 16) & 1u)) >> 16;
}
__device__ __forceinline__ unsigned pack_bf16(float lo, float hi) {
    return bf16_rne(lo) | (bf16_rne(hi) << 16);
}
// fast pack: round-half-up + byte-perm
__device__ __forceinline__ unsigned pk_hu(float lo, float hi) {
    unsigned a = __float_as_uint(lo) + 0x8000u;
    unsigned b = __float_as_uint(hi) + 0x8000u;
    return __builtin_amdgcn_perm(b, a, 0x07060302u);
}
__device__ __forceinline__ unsigned pmul_fast(unsigned a, unsigned b) {
    return pk_hu(bflo(a) * bflo(b), bfhi(a) * bfhi(b));
}

// ===========================================================================
// k_prep: scalars + wIt + wOt.  grid 232x256
// ===========================================================================
__global__ __launch_bounds__(256)
void k_prep(const float* __restrict__ g1, const float* __restrict__ b1,
            const float* __restrict__ m1, const float* __restrict__ v1,
            const float* __restrict__ w_in,
            const float* __restrict__ gi, const float* __restrict__ bi,
            const float* __restrict__ mi, const float* __restrict__ vi,
            const float* __restrict__ ge, const float* __restrict__ be,
            const float* __restrict__ me, const float* __restrict__ ve,
            const float* __restrict__ w_out,
            const float* __restrict__ go, const float* __restrict__ bo,
            const float* __restrict__ mo, const float* __restrict__ vo,
            float* __restrict__ s1, float* __restrict__ b1c,
            float* __restrict__ biasI, float* __restrict__ biasE, float* __restrict__ biasO,
            unsigned* __restrict__ wIt, unsigned* __restrict__ wOt)
{
    int i = blockIdx.x * 256 + threadIdx.x;

    if (i < 640) {
        float s = g1[i] * rsqrtf(v1[i] + BN_EPS);
        s1[i] = s; b1c[i] = b1[i] - m1[i] * s;
    } else if (i < 704) {
        int c = i - 640;
        float s = gi[c] * rsqrtf(vi[c] + BN_EPS);
        biasI[c] = bi[c] - mi[c] * s;
    } else if (i < 1344) {
        int c = i - 704;
        float s = ge[c] * rsqrtf(ve[c] + BN_EPS);
        biasE[c] = be[c] - me[c] * s;
    } else if (i < 1984) {
        int c = i - 1344;
        float s = go[c] * rsqrtf(vo[c] + BN_EPS);
        biasO[c] = bo[c] - mo[c] * s;
    }

    if (i >= 2048 && i < 7168) {         // wIt: 20 kc x 256 units
        int u = i - 2048;
        int kc = u >> 8, w = u & 255;
        int mf = w >> 7, kh = (w >> 6) & 1, sl = w & 63;
        int oc = mf * 32 + (sl & 31);
        int k0 = kc * 32 + kh * 16 + (sl >> 5) * 8;
        float sc = gi[oc] * rsqrtf(vi[oc] + BN_EPS);
        unsigned d[4];
#pragma unroll
        for (int q = 0; q < 4; q++)
            d[q] = pack_bf16(w_in[oc * 640 + k0 + 2 * q] * sc,
                             w_in[oc * 640 + k0 + 2 * q + 1] * sc);
        ((uint4*)wIt)[u] = make_uint4(d[0], d[1], d[2], d[3]);
    }

    if (i >= 8192 && i < 59392) {        // wOt: 5 mt x 20 kc x 512 units
        int u = i - 8192;
        int ci = u >> 9, w = u & 511;
        int mt = ci / 20, kc = ci - mt * 20;
        int mf = w >> 7, kh = (w >> 6) & 1, sl = w & 63;
        int oc = mt * 128 + mf * 32 + (sl & 31);
        int k0 = kc * 32 + kh * 16 + (sl >> 5) * 8;
        float sc = go[oc] * rsqrtf(vo[oc] + BN_EPS);
        unsigned d[4];
#pragma unroll
        for (int q = 0; q < 4; q++)
            d[q] = pack_bf16(w_out[oc * 640 + k0 + 2 * q] * sc,
                             w_out[oc * 640 + k0 + 2 * q + 1] * sc);
        ((uint4*)wOt)[u] = make_uint4(d[0], d[1], d[2], d[3]);
    }
}

// ===========================================================================
// k_prepE: wEt via per-oc LDS staged row. 640 blocks.
// ===========================================================================
__global__ __launch_bounds__(256)
void k_prepE(const float* __restrict__ w_emb,
             const float* __restrict__ ge, const float* __restrict__ ve,
             unsigned* __restrict__ wEt)
{
    __shared__ float row[1664];
    const int tid = threadIdx.x;
    const int oc = blockIdx.x;

#pragma unroll
    for (int it = 0; it < 2; it++) {
        int u = it * 256 + tid;
        if (u < 416)
            ((float4*)row)[u] = ((const float4*)&w_emb[(size_t)oc * 1664])[u];
    }
    __syncthreads();

    if (tid < 208) {
        int kc = tid >> 2, kh = (tid >> 1) & 1, ksub = tid & 1;
        int k0 = kc * 32 + kh * 16 + ksub * 8;
        float sc = ge[oc] * rsqrtf(ve[oc] + BN_EPS);
        float v[8];
#pragma unroll
        for (int j = 0; j < 8; j++) {
            int kgp = k0 + j;
            int orig;
            if (kgp < 64) orig = kgp;
            else { int t = kgp - 64; orig = 64 + (t & 63) * 25 + (t >> 6); }
            v[j] = row[orig] * sc;
        }
        int mt = oc >> 7, mf = (oc >> 5) & 3;
        int idx = (mt * 52 + kc) * 512 + (mf * 2 + kh) * 64 + ksub * 32 + (oc & 31);
        ((uint4*)wEt)[idx] = make_uint4(pack_bf16(v[0], v[1]), pack_bf16(v[2], v[3]),
                                        pack_bf16(v[4], v[5]), pack_bf16(v[6], v[7]));
    }
}

// ===========================================================================
// k_identity: 512 thr, K-split (waves 0-3: K[0,320), waves 4-7: K[320,640)),
// fp32 LDS reduction, then bias+relu+l2norm epilogue.
// ===========================================================================
__global__ __launch_bounds__(512, 1)
void k_identity(const float* __restrict__ x,
                const float* __restrict__ s1, const float* __restrict__ b1c,
                const unsigned* __restrict__ wIt, const float* __restrict__ biasI,
                unsigned* __restrict__ ident)
{
    __shared__ short smem[2][4096];       // per-half: A[0,2048) B[2048,4096)
    __shared__ float Tpart[64 * 65];      // half-1 partial (padded, conflict-free)
    __shared__ float T[64 * 68];
    __shared__ float inv[64];

    const int tid  = threadIdx.x;
    const int half = tid >> 8;
    const int t    = tid & 255;
    const int l = t & 63, wv = t >> 6;
    const int mf = wv >> 1, nf = wv & 1;
    const int p0 = blockIdx.x * 64;
    const int b = p0 >> 10, hw0 = p0 & 1023;

    f32x16 acc;
#pragma unroll
    for (int r = 0; r < 16; r++) acc[r] = 0.f;

    for (int i = 0; i < 10; i++) {
        const int kc = half * 10 + i;
        uint4 av = ((const uint4*)wIt)[kc * 256 + t];
        int bnf = t >> 7, bkh = (t >> 6) & 1, sl = t & 63;
        int px = bnf * 32 + (sl & 31);
        int ch0 = kc * 32 + bkh * 16 + (sl >> 5) * 8;
        float4 sA = *(const float4*)&s1[ch0], sB = *(const float4*)&s1[ch0 + 4];
        float4 bA = *(const float4*)&b1c[ch0], bB = *(const float4*)&b1c[ch0 + 4];
        float vv[8];
        const float* xp = &x[((size_t)b * 640 + ch0) * 1024 + hw0 + px];
        vv[0] = fmaxf(fmaf(xp[0], sA.x, bA.x), 0.f);
        vv[1] = fmaxf(fmaf(xp[1024], sA.y, bA.y), 0.f);
        vv[2] = fmaxf(fmaf(xp[2048], sA.z, bA.z), 0.f);
        vv[3] = fmaxf(fmaf(xp[3072], sA.w, bA.w), 0.f);
        vv[4] = fmaxf(fmaf(xp[4096], sB.x, bB.x), 0.f);
        vv[5] = fmaxf(fmaf(xp[5120], sB.y, bB.y), 0.f);
        vv[6] = fmaxf(fmaf(xp[6144], sB.z, bB.z), 0.f);
        vv[7] = fmaxf(fmaf(xp[7168], sB.w, bB.w), 0.f);
        uint4 bvpk = make_uint4(pack_bf16(vv[0], vv[1]), pack_bf16(vv[2], vv[3]),
                                pack_bf16(vv[4], vv[5]), pack_bf16(vv[6], vv[7]));
        __syncthreads();
        ((uint4*)smem[half])[t] = av;
        ((uint4*)(smem[half] + 2048))[t] = bvpk;
        __syncthreads();
#pragma unroll
        for (int kh = 0; kh < 2; kh++) {
            short8 a  = *(const short8*)&smem[half][((mf * 2 + kh) * 64 + l) * 8];
            short8 bb = *(const short8*)&smem[half][2048 + ((nf * 2 + kh) * 64 + l) * 8];
            acc = __builtin_amdgcn_mfma_f32_32x32x16_bf16(a, bb, acc, 0, 0, 0);
        }
    }
    // ---- K-half reduction
    if (half == 1) {
#pragma unroll
        for (int r = 0; r < 16; r++) {
            int m = mf * 32 + (r & 3) + 8 * (r >> 2) + 4 * (l >> 5);
            int px = nf * 32 + (l & 31);
            Tpart[px * 65 + m] = acc[r];
        }
    }
    __syncthreads();
    if (half == 0) {
#pragma unroll
        for (int r = 0; r < 16; r++) {
            int m = mf * 32 + (r & 3) + 8 * (r >> 2) + 4 * (l >> 5);
            int px = nf * 32 + (l & 31);
            float v = acc[r] + Tpart[px * 65 + m];
            T[px * 68 + m] = fmaxf(v + biasI[m], 0.f);
        }
    }
    __syncthreads();
    if (tid < 64) {
        float sum = 0.f;
#pragma unroll 8
        for (int c = 0; c < 64; c++) { float v = T[tid * 68 + c]; sum = fmaf(v, v, sum); }
        inv[tid] = 1.f / fmaxf(sqrtf(sum), 1e-12f);
    }
    __syncthreads();
    {
        int px = tid >> 3, q = tid & 7;
        float iv = inv[px];
        unsigned d[4];
#pragma unroll
        for (int t2 = 0; t2 < 4; t2++)
            d[t2] = pack_bf16(T[px * 68 + q * 8 + 2 * t2] * iv,
                              T[px * 68 + q * 8 + 2 * t2 + 1] * iv);
        *(uint4*)&ident[(size_t)(p0 + px) * 32 + q * 4] = make_uint4(d[0], d[1], d[2], d[3]);
    }
}

// ===========================================================================
// k_feat: 512 thr (8 waves). slab(6x36 halo) -> invD -> ctrs -> 52 kc feat
// in B-frag order (2 kc per iteration). grid 256 (or chunked).
// ===========================================================================
#define FS_SLAB 0          // 216 spx * 72 shorts
#define FS_CTRS 15552      // 64 px * 72 shorts   (total 20160 shorts)
__global__ __launch_bounds__(512, 1)
void k_feat(const unsigned* __restrict__ ident, unsigned* __restrict__ featC, int ptBase)
{
    __shared__ short smem[20160];
    __shared__ float invDs[64];

    const int tid = threadIdx.x;
    const int pt = ptBase + blockIdx.x;
    const int b = pt >> 4, r0 = (pt & 15) * 2;

    // ---- slab load (zero-padded halo): 1728 uint4 units
#pragma unroll
    for (int it = 0; it < 4; it++) {
        int u = it * 512 + tid;
        if (u < 1728) {
            int spx = u >> 3, q = u & 7;
            int sr = spx / 36, sc = spx - sr * 36;
            int r = r0 + sr - 2, c = sc - 2;
            uint4 v = make_uint4(0u, 0u, 0u, 0u);
            if (r >= 0 && r < 32 && c >= 0 && c < 32)
                v = *(const uint4*)&ident[((size_t)(b * 1024 + r * 32 + c) * 64 + q * 8) / 2];
            *(uint4*)&smem[FS_SLAB + spx * 72 + q * 8] = v;
        }
    }
    __syncthreads();

    // ---- invD: 8 threads / px (8 channels each)
    {
        int px = tid >> 3, part = tid & 7;
        int rh = px >> 5, rw = px & 31;
        float ctr[8];
        const unsigned* cp = (const unsigned*)&smem[FS_SLAB + ((rh + 2) * 36 + rw + 2) * 72 + part * 8];
#pragma unroll
        for (int d = 0; d < 4; d++) { ctr[2 * d] = bflo(cp[d]); ctr[2 * d + 1] = bfhi(cp[d]); }
        float sum = 0.f;
#pragma unroll
        for (int k = 0; k < 25; k++) {
            const int kh = k / 5, kw = k % 5;
            const unsigned* nb = (const unsigned*)&smem[FS_SLAB + ((rh + kh) * 36 + rw + kw) * 72 + part * 8];
#pragma unroll
            for (int d = 0; d < 4; d++) {
                float q0 = bflo(nb[d]) * ctr[2 * d];
                float q1 = bfhi(nb[d]) * ctr[2 * d + 1];
                sum = fmaf(q0, q0, sum); sum = fmaf(q1, q1, sum);
            }
        }
        sum += __shfl_xor(sum, 1);
        sum += __shfl_xor(sum, 2);
        sum += __shfl_xor(sum, 4);
        if (part == 0) invDs[px] = rsqrtf(sum + 1e-6f);
    }
    __syncthreads();

    // ---- ctrs = center * invD (bf16): 512 units
    {
        int px = tid >> 3, q = tid & 7;
        int spx = ((px >> 5) + 2) * 36 + (px & 31) + 2;
        const unsigned* src = (const unsigned*)&smem[FS_SLAB + spx * 72 + q * 8];
        float iv = invDs[px];
        unsigned d[4];
#pragma unroll
        for (int dd = 0; dd < 4; dd++)
            d[dd] = pk_hu(bflo(src[dd]) * iv, bfhi(src[dd]) * iv);
        *(uint4*)&smem[FS_CTRS + px * 72 + q * 8] = make_uint4(d[0], d[1], d[2], d[3]);
    }
    __syncthreads();

    // ---- feat gen: 2 kc per iteration (kc = 2*it + (tid>>8))
    const int t = tid & 255;
    const int hf = t >> 7, bkh = (t >> 6) & 1, sl = t & 63;
    const int pxl = hf * 32 + (sl & 31);
    const int cl = bkh * 16 + (sl >> 5) * 8;
    const int spxC = (hf + 2) * 36 + (sl & 31) + 2;
    const int kcH = tid >> 8;
    uint4* dst = (uint4*)featC + (size_t)blockIdx.x * 52 * 256 + t;

    for (int it = 0; it < 26; it++) {
        int kc = it * 2 + kcH;
        uint4 f;
        if (kc < 2) {
            f = *(const uint4*)&smem[FS_SLAB + spxC * 72 + kc * 32 + cl];
        } else {
            int idx = kc - 2;
            int ksp = idx >> 1;
            int cb = (idx & 1) * 32 + cl;
            int kho = ksp / 5, kwo = ksp - kho * 5;
            int spx = (hf + kho) * 36 + (sl & 31) + kwo;
            const unsigned* nb = (const unsigned*)&smem[FS_SLAB + spx * 72 + cb];
            const unsigned* ct = (const unsigned*)&smem[FS_CTRS + pxl * 72 + cb];
            f = make_uint4(pmul_fast(nb[0], ct[0]), pmul_fast(nb[1], ct[1]),
                           pmul_fast(nb[2], ct[2]), pmul_fast(nb[3], ct[3]));
        }
        dst[kc * 256] = f;
    }
}

// ===========================================================================
// k_emb: pure GEMM with ping-pong register prefetch. grid (nt, mt=5).
// ===========================================================================
__device__ __forceinline__ void ld_frag(const uint4* __restrict__ A, const uint4* __restrict__ B,
                                        int kc, int mh, int nh, int l,
                                        uint4 av[2][2], uint4 bv[2][2])
{
#pragma unroll
    for (int mi = 0; mi < 2; mi++)
#pragma unroll
        for (int kh = 0; kh < 2; kh++)
            av[mi][kh] = A[(size_t)kc * 512 + ((mh * 2 + mi) * 2 + kh) * 64 + l];
#pragma unroll
    for (int ni = 0; ni < 2; ni++) {
        int bnf = 2 * nh + ni;
#pragma unroll
        for (int kh = 0; kh < 2; kh++)
            bv[ni][kh] = B[((size_t)(bnf >> 1) * 52 + kc) * 256 + ((bnf & 1) << 7) + (kh << 6) + l];
    }
}
__device__ __forceinline__ void do_mfma(uint4 av[2][2], uint4 bv[2][2], f32x16 acc[2][2])
{
#pragma unroll
    for (int kh = 0; kh < 2; kh++) {
        acc[0][0] = __builtin_amdgcn_mfma_f32_32x32x16_bf16(*(short8*)&av[0][kh], *(short8*)&bv[0][kh], acc[0][0], 0, 0, 0);
        acc[0][1] = __builtin_amdgcn_mfma_f32_32x32x16_bf16(*(short8*)&av[0][kh], *(short8*)&bv[1][kh], acc[0][1], 0, 0, 0);
        acc[1][0] = __builtin_amdgcn_mfma_f32_32x32x16_bf16(*(short8*)&av[1][kh], *(short8*)&bv[0][kh], acc[1][0], 0, 0, 0);
        acc[1][1] = __builtin_amdgcn_mfma_f32_32x32x16_bf16(*(short8*)&av[1][kh], *(short8*)&bv[1][kh], acc[1][1], 0, 0, 0);
    }
}

__global__ __launch_bounds__(256, 2)
void k_emb(const unsigned* __restrict__ featC, const unsigned* __restrict__ wEt,
           const float* __restrict__ biasE, unsigned* __restrict__ eG, int ntBase)
{
    __shared__ short Ep[128 * 136];

    const int tid = threadIdx.x;
    const int l = tid & 63, wv = tid >> 6;
    const int mh = wv >> 1, nh = wv & 1;
    const int ntL = blockIdx.x, mt = blockIdx.y;

    f32x16 acc[2][2];
#pragma unroll
    for (int i = 0; i < 2; i++)
#pragma unroll
        for (int j = 0; j < 2; j++)
#pragma unroll
            for (int r = 0; r < 16; r++) acc[i][j][r] = 0.f;

    const uint4* A = (const uint4*)wEt + (size_t)(mt * 52) * 512;
    const uint4* B = (const uint4*)featC + (size_t)ntL * 2 * 52 * 256;

    uint4 a0[2][2], b0[2][2], a1[2][2], b1[2][2];
    ld_frag(A, B, 0, mh, nh, l, a0, b0);
    for (int kc = 0; kc < 52; kc += 2) {
        ld_frag(A, B, kc + 1, mh, nh, l, a1, b1);
        do_mfma(a0, b0, acc);
        if (kc + 2 < 52) ld_frag(A, B, kc + 2, mh, nh, l, a0, b0);
        do_mfma(a1, b1, acc);
    }

    // ---- epilogue: bias+relu -> Ep[px][136]
#pragma unroll
    for (int mi = 0; mi < 2; mi++)
#pragma unroll
        for (int ni = 0; ni < 2; ni++) {
            int px = (nh * 2 + ni) * 32 + (l & 31);
#pragma unroll
            for (int r = 0; r < 16; r += 2) {
                int m = (mh * 2 + mi) * 32 + (r & 3) + 8 * (r >> 2) + 4 * (l >> 5);
                float v0 = fmaxf(acc[mi][ni][r] + biasE[mt * 128 + m], 0.f);
                float v1 = fmaxf(acc[mi][ni][r + 1] + biasE[mt * 128 + m + 1], 0.f);
                *(unsigned*)&Ep[px * 136 + m] = pack_bf16(v0, v1);
            }
        }
    __syncthreads();
    // ---- write e in k_out B-frag order
#pragma unroll
    for (int it = 0; it < 8; it++) {
        int w = it * 256 + tid;
        int oct = w >> 7, pxl = w & 127;
        uint4 v = *(const uint4*)&Ep[pxl * 136 + oct * 8];
        int kcp = mt * 4 + (oct >> 2);
        int bkh = (oct >> 1) & 1, ksub = oct & 1;
        int ptg = (ntBase + ntL) * 2 + (pxl >> 6);
        int hf = (pxl >> 5) & 1, sl2 = ksub * 32 + (pxl & 31);
        ((uint4*)eG)[((size_t)ptg * 20 + kcp) * 256 + (hf << 7) + (bkh << 6) + sl2] = v;
    }
}

// ===========================================================================
// k_out: pure GEMM with ping-pong prefetch. grid (128, 5).
// ===========================================================================
__device__ __forceinline__ void ld_fragO(const uint4* __restrict__ A, const uint4* __restrict__ B,
                                         int kc, int mh, int nh, int l,
                                         uint4 av[2][2], uint4 bv[2][2])
{
#pragma unroll
    for (int mi = 0; mi < 2; mi++)
#pragma unroll
        for (int kh = 0; kh < 2; kh++)
            av[mi][kh] = A[(size_t)kc * 512 + ((mh * 2 + mi) * 2 + kh) * 64 + l];
#pragma unroll
    for (int ni = 0; ni < 2; ni++) {
        int bnf = 2 * nh + ni;
#pragma unroll
        for (int kh = 0; kh < 2; kh++)
            bv[ni][kh] = B[((size_t)(bnf >> 1) * 20 + kc) * 256 + ((bnf & 1) << 7) + (kh << 6) + l];
    }
}

__global__ __launch_bounds__(256, 2)
void k_out(const unsigned* __restrict__ eG, const unsigned* __restrict__ wOt,
           const float* __restrict__ biasO, float* __restrict__ out)
{
    const int tid = threadIdx.x;
    const int l = tid & 63, wv = tid >> 6;
    const int mh = wv >> 1, nh = wv & 1;
    const int nt = blockIdx.x, mt = blockIdx.y;
    const int p0 = nt * 128;
    const int b = p0 >> 10, hw0 = p0 & 1023;

    f32x16 acc[2][2];
#pragma unroll
    for (int i = 0; i < 2; i++)
#pragma unroll
        for (int j = 0; j < 2; j++)
#pragma unroll
            for (int r = 0; r < 16; r++) acc[i][j][r] = 0.f;

    const uint4* A = (const uint4*)wOt + (size_t)(mt * 20) * 512;
    const uint4* B = (const uint4*)eG + (size_t)nt * 2 * 20 * 256;

    uint4 a0[2][2], b0[2][2], a1[2][2], b1[2][2];
    ld_fragO(A, B, 0, mh, nh, l, a0, b0);
    for (int kc = 0; kc < 20; kc += 2) {
        ld_fragO(A, B, kc + 1, mh, nh, l, a1, b1);
        do_mfma(a0, b0, acc);
        if (kc + 2 < 20) ld_fragO(A, B, kc + 2, mh, nh, l, a0, b0);
        do_mfma(a1, b1, acc);
    }
#pragma unroll
    for (int mi = 0; mi < 2; mi++)
#pragma unroll
        for (int ni = 0; ni < 2; ni++) {
            int pxl = (nh * 2 + ni) * 32 + (l & 31);
#pragma unroll
            for (int r = 0; r < 16; r++) {
                int oc = mt * 128 + (mh * 2 + mi) * 32 + (r & 3) + 8 * (r >> 2) + 4 * (l >> 5);
                out[((size_t)b * 640 + oc) * 1024 + hw0 + pxl] = acc[mi][ni][r] + biasO[oc];
            }
        }
}

// ===========================================================================
extern "C" void kernel_launch(void* const* d_in, const int* in_sizes, int n_in,
                              void* d_out, int out_size, void* d_ws, size_t ws_size,
                              hipStream_t stream)
{
    const float* x    = (const float*)d_in[0];
    const float* g1   = (const float*)d_in[1];
    const float* b1   = (const float*)d_in[2];
    const float* m1   = (const float*)d_in[3];
    const float* v1   = (const float*)d_in[4];
    const float* w_in = (const float*)d_in[5];
    const float* gi   = (const float*)d_in[6];
    const float* bi   = (const float*)d_in[7];
    const float* mi   = (const float*)d_in[8];
    const float* vi   = (const float*)d_in[9];
    const float* w_emb= (const float*)d_in[10];
    const float* ge   = (const float*)d_in[11];
    const float* be   = (const float*)d_in[12];
    const float* me   = (const float*)d_in[13];
    const float* ve   = (const float*)d_in[14];
    const float* w_out= (const float*)d_in[15];
    const float* go   = (const float*)d_in[16];
    const float* bo   = (const float*)d_in[17];
    const float* mo   = (const float*)d_in[18];
    const float* vo   = (const float*)d_in[19];

    char* ws = (char*)d_ws;
    float*    s1    = (float*)(ws + 0);
    float*    b1c   = (float*)(ws + 2560);
    float*    biasI = (float*)(ws + 5120);
    float*    biasE = (float*)(ws + 5376);
    float*    biasO = (float*)(ws + 7936);
    unsigned* wIt   = (unsigned*)(ws + 16384);
    unsigned* wOt   = (unsigned*)(ws + 98304);
    unsigned* wEt   = (unsigned*)(ws + 917504);
    unsigned* ident = (unsigned*)(ws + 3047424);
    unsigned* eG    = (unsigned*)(ws + 5144576);   // ends 26,116,096
    float*    out   = (float*)d_out;

    const size_t featFullOff = 26116096ull;
    const size_t featFullBytes = 256ull * 52 * 256 * 16;   // 54,525,952

    k_prep<<<232, 256, 0, stream>>>(g1, b1, m1, v1, w_in, gi, bi, mi, vi,
                                    ge, be, me, ve, w_out, go, bo, mo, vo,
                                    s1, b1c, biasI, biasE, biasO, wIt, wOt);
    k_prepE<<<640, 256, 0, stream>>>(w_emb, ge, ve, wEt);
    k_identity<<<256, 512, 0, stream>>>(x, s1, b1c, wIt, biasI, ident);

    if (ws_size >= featFullOff + featFullBytes) {
        unsigned* featC = (unsigned*)(ws + featFullOff);
        k_feat<<<256, 512, 0, stream>>>(ident, featC, 0);
        k_emb<<<dim3(128, 5), 256, 0, stream>>>(featC, wEt, biasE, eG, 0);
    } else {
        // chunked fallback: featG chunk (4 tiles) in dead wIt/wOt region;
        // wOt regenerated afterwards.
        unsigned* featC = (unsigned*)(ws + 16384);
        for (int c = 0; c < 64; c++) {
            k_feat<<<4, 512, 0, stream>>>(ident, featC, c * 4);
            k_emb<<<dim3(2, 5), 256, 0, stream>>>(featC, wEt, biasE, eG, c * 2);
        }
        k_prep<<<232, 256, 0, stream>>>(g1, b1, m1, v1, w_in, gi, bi, mi, vi,
                                        ge, be, me, ve, w_out, go, bo, mo, vo,
                                        s1, b1c, biasI, biasE, biasO, wIt, wOt);
    }
    k_out<<<dim3(128, 5), 256, 0, stream>>>(eG, wOt, biasO, out);
}